// Round 4
// baseline (568.942 us; speedup 1.0000x reference)
//
#include <hip/hip_runtime.h>
#include <math.h>

#define LQ 2048
#define DM 1024
#define NH 16
#define DH 64
#define UU 38
#define NBH 64            // B*NH = 4*16
#define SCALE 0.125f      // 1/sqrt(64)

typedef _Float16 f16x8 __attribute__((ext_vector_type(8)));
typedef _Float16 f16x4 __attribute__((ext_vector_type(4)));
typedef float f32x4 __attribute__((ext_vector_type(4)));

// workspace layout (bytes):
//   [0, 1MB)          vals : 131072 doubles (KL per query)
//   [1MB, +9728)      sel  : 64*38 ints
//   [+9728, +19456)   l3   : 64*38 floats
//   [+19456, +642048) acc  : 64*38*64 floats
#define WS_BYTES (1048576 + 19456 + 622592)

// ---------------------------------------------------------------------------
// Kernel 1: KL via fp16-split MFMA (unchanged from round 3; ~verified).
// ---------------------------------------------------------------------------
__global__ __launch_bounds__(256) void kl_mfma(const float* __restrict__ Q,
                                               const float* __restrict__ K,
                                               double* __restrict__ vals) {
  int bh = blockIdx.x & 63;
  int qc = blockIdx.x >> 6;
  int b = bh >> 4, h = bh & 15;
  int t = threadIdx.x;
  int lane = t & 63, w = t >> 6;
  int quad = lane >> 4, l15 = lane & 15;

  __shared__ __align__(16) char smem[34816];
  float* qs = (float*)smem;

#pragma unroll
  for (int i = 0; i < 8; ++i) {
    int idx = i * 256 + t;
    int row = idx >> 4, d4 = idx & 15;
    float4 v = *(const float4*)(Q + ((size_t)(b * LQ + qc * 128 + row)) * DM + h * DH + d4 * 4);
    *(float4*)(qs + row * 68 + d4 * 4) = v;
  }
  __syncthreads();

  f16x8 ahi[2][2], alo[2][2];
#pragma unroll
  for (int qt = 0; qt < 2; ++qt)
#pragma unroll
    for (int c = 0; c < 2; ++c) {
      const float* p = qs + (w * 32 + qt * 16 + l15) * 68 + c * 32 + quad * 8;
      f16x8 hi, lo;
#pragma unroll
      for (int j = 0; j < 8; ++j) {
        float x = p[j];
        _Float16 hh = (_Float16)x;
        hi[j] = hh;
        lo[j] = (_Float16)(x - (float)hh);
      }
      ahi[qt][c] = hi;
      alo[qt][c] = lo;
    }
  __syncthreads();

  _Float16* khi = (_Float16*)smem;        // [64][88]
  _Float16* klo = khi + 64 * 88;

  double l64[2][4], t64[2][4];
#pragma unroll
  for (int qt = 0; qt < 2; ++qt)
#pragma unroll
    for (int r = 0; r < 4; ++r) { l64[qt][r] = 0.0; t64[qt][r] = 0.0; }

  for (int kb = 0; kb < LQ; kb += 64) {
    __syncthreads();
#pragma unroll
    for (int i = 0; i < 4; ++i) {
      int idx = i * 256 + t;
      int key = idx >> 4, d4 = idx & 15;
      float4 v = *(const float4*)(K + ((size_t)(b * LQ + kb + key)) * DM + h * DH + d4 * 4);
      f16x4 hv, lv;
      hv[0] = (_Float16)v.x; lv[0] = (_Float16)(v.x - (float)hv[0]);
      hv[1] = (_Float16)v.y; lv[1] = (_Float16)(v.y - (float)hv[1]);
      hv[2] = (_Float16)v.z; lv[2] = (_Float16)(v.z - (float)hv[2]);
      hv[3] = (_Float16)v.w; lv[3] = (_Float16)(v.w - (float)hv[3]);
      *(f16x4*)(khi + key * 88 + d4 * 4) = hv;
      *(f16x4*)(klo + key * 88 + d4 * 4) = lv;
    }
    __syncthreads();

    float l32[2][4], t32[2][4];
#pragma unroll
    for (int qt = 0; qt < 2; ++qt)
#pragma unroll
      for (int r = 0; r < 4; ++r) { l32[qt][r] = 0.f; t32[qt][r] = 0.f; }

#pragma unroll
    for (int kt = 0; kt < 4; ++kt) {
      const _Float16* bp = khi + (kt * 16 + l15) * 88 + quad * 8;
      const _Float16* bp2 = klo + (kt * 16 + l15) * 88 + quad * 8;
      f16x8 bhi0 = *(const f16x8*)bp;
      f16x8 bhi1 = *(const f16x8*)(bp + 32);
      f16x8 blo0 = *(const f16x8*)bp2;
      f16x8 blo1 = *(const f16x8*)(bp2 + 32);
#pragma unroll
      for (int qt = 0; qt < 2; ++qt) {
        f32x4 cacc = {0.f, 0.f, 0.f, 0.f};
        cacc = __builtin_amdgcn_mfma_f32_16x16x32_f16(alo[qt][0], bhi0, cacc, 0, 0, 0);
        cacc = __builtin_amdgcn_mfma_f32_16x16x32_f16(alo[qt][1], bhi1, cacc, 0, 0, 0);
        cacc = __builtin_amdgcn_mfma_f32_16x16x32_f16(ahi[qt][0], blo0, cacc, 0, 0, 0);
        cacc = __builtin_amdgcn_mfma_f32_16x16x32_f16(ahi[qt][1], blo1, cacc, 0, 0, 0);
        cacc = __builtin_amdgcn_mfma_f32_16x16x32_f16(ahi[qt][0], bhi0, cacc, 0, 0, 0);
        cacc = __builtin_amdgcn_mfma_f32_16x16x32_f16(ahi[qt][1], bhi1, cacc, 0, 0, 0);
#pragma unroll
        for (int r = 0; r < 4; ++r) {
          float s = cacc[r] * SCALE;
          float e = __expf(s);
          l32[qt][r] += e;
          t32[qt][r] = fmaf(s, e, t32[qt][r]);
        }
      }
    }
#pragma unroll
    for (int qt = 0; qt < 2; ++qt)
#pragma unroll
      for (int r = 0; r < 4; ++r) {
        l64[qt][r] += (double)l32[qt][r];
        t64[qt][r] += (double)t32[qt][r];
      }
  }

#pragma unroll
  for (int qt = 0; qt < 2; ++qt)
#pragma unroll
    for (int r = 0; r < 4; ++r) {
      double lv = l64[qt][r], tv = t64[qt][r];
#pragma unroll
      for (int m = 1; m < 16; m <<= 1) {
        lv += __shfl_xor(lv, m);
        tv += __shfl_xor(tv, m);
      }
      if (l15 == 0) {
        int qg = qc * 128 + w * 32 + qt * 16 + quad * 4 + r;
        vals[(size_t)bh * LQ + qg] = tv / lv - log(lv) + 7.624618986159398;
      }
    }
}

// ---------------------------------------------------------------------------
// Kernel 2: per-(b,h) top-38 by KL (fp64), descending, ties -> lower index.
// ---------------------------------------------------------------------------
__global__ __launch_bounds__(256) void topk_kernel(const double* __restrict__ vals_in,
                                                   int* __restrict__ idxout) {
  int bh = blockIdx.x;
  int t = threadIdx.x;
  __shared__ double vals[LQ];
  __shared__ double bv[4];
  __shared__ int bi[4];
  for (int i = t; i < LQ; i += 256) vals[i] = vals_in[(size_t)bh * LQ + i];
  __syncthreads();
  for (int u = 0; u < UU; ++u) {
    double best = -INFINITY;
    int besti = LQ;
    for (int i = t; i < LQ; i += 256) {
      double v = vals[i];
      if (v > best) { best = v; besti = i; }
    }
#pragma unroll
    for (int off = 32; off > 0; off >>= 1) {
      double ov = __shfl_down(best, off);
      int oi = __shfl_down(besti, off);
      if (ov > best || (ov == best && oi < besti)) { best = ov; besti = oi; }
    }
    if ((t & 63) == 0) { bv[t >> 6] = best; bi[t >> 6] = besti; }
    __syncthreads();
    if (t == 0) {
      double fb = bv[0]; int fi = bi[0];
      for (int w2 = 1; w2 < 4; ++w2) {
        if (bv[w2] > fb || (bv[w2] == fb && bi[w2] < fi)) { fb = bv[w2]; fi = bi[w2]; }
      }
      idxout[bh * UU + u] = fi;
      vals[fi] = -INFINITY;
    }
    __syncthreads();
  }
}

// ---------------------------------------------------------------------------
// Kernel 3: sparse attention, occupancy-tiled. Grid = 64 bh x 16 key-splits
// (1024 blocks); block = 128 keys in 4 tiles of 32. LDS ~31 KB -> 5 blocks/CU
// by LDS; __launch_bounds__(256,4) caps VGPR <= 128 -> 4 blocks/CU (16
// waves). Phase 1: each wave computes e^s for 8 keys (lane = query u),
// stores to els (stride 33 -> (lane+j)%32 banks, conflict-free). Phase 2:
// each wave re-reads els and accumulates P*V for its 16 dims only (o = 16
// VGPRs instead of 64). Denominator + P*V partials merged via global atomics.
// ---------------------------------------------------------------------------
__global__ __launch_bounds__(256, 4) void attn_kernel(const float* __restrict__ Q,
                                                      const float* __restrict__ K,
                                                      const float* __restrict__ V,
                                                      const int* __restrict__ sel,
                                                      float* __restrict__ wout,
                                                      float* __restrict__ l3,
                                                      float* __restrict__ acc) {
  int bh = blockIdx.x >> 4;
  int ks = blockIdx.x & 15;
  int b = bh >> 4, h = bh & 15;
  int t = threadIdx.x;
  int lane = t & 63, w = t >> 6;

  __shared__ float4 kt[32 * 16];   // 8 KB
  __shared__ float4 vt[32 * 16];   // 8 KB
  __shared__ float qs[UU * 68];    // 10.3 KB
  __shared__ float els[UU * 33];   // 5.0 KB
  __shared__ int sidx[UU];

  if (t < UU) sidx[t] = sel[bh * UU + t];
  __syncthreads();
  for (int i = t; i < UU * 16; i += 256) {
    int u = i >> 4, d4 = i & 15;
    *(float4*)(qs + u * 68 + d4 * 4) =
        *(const float4*)(Q + ((size_t)(b * LQ + sidx[u])) * DM + h * DH + d4 * 4);
  }
  __syncthreads();

  bool act = lane < UU;
  float4 qv[16];
  if (act) {
    const float4* qp = (const float4*)(qs + lane * 68);
#pragma unroll
    for (int i = 0; i < 16; ++i) qv[i] = qp[i];
  } else {
#pragma unroll
    for (int i = 0; i < 16; ++i) qv[i] = make_float4(0.f, 0.f, 0.f, 0.f);
  }

  float l_acc = 0.f;
  float4 o4[4];
#pragma unroll
  for (int i = 0; i < 4; ++i) o4[i] = make_float4(0.f, 0.f, 0.f, 0.f);

  for (int tile = 0; tile < 4; ++tile) {
    int k0 = ks * 128 + tile * 32;
    __syncthreads();   // prev phase2/dump done before restaging kt/vt
#pragma unroll
    for (int i = 0; i < 2; ++i) {
      int idx = i * 256 + t;
      int kk = idx >> 4, d4 = idx & 15;
      size_t roff = ((size_t)(b * LQ + k0 + kk)) * DM + h * DH;
      kt[idx] = ((const float4*)(K + roff))[d4];
      vt[idx] = ((const float4*)(V + roff))[d4];
    }
    __syncthreads();

    // phase 1: scores for this wave's 8 keys; lane = query
#pragma unroll
    for (int jj = 0; jj < 8; ++jj) {
      int j = w * 8 + jj;
      const float4* krow = &kt[j * 16];
      float4 a = make_float4(0.f, 0.f, 0.f, 0.f);
      float4 c = make_float4(0.f, 0.f, 0.f, 0.f);
#pragma unroll
      for (int d4 = 0; d4 < 16; d4 += 2) {
        float4 k0v = krow[d4];
        float4 k1v = krow[d4 + 1];
        a.x = fmaf(qv[d4].x, k0v.x, a.x);
        a.y = fmaf(qv[d4].y, k0v.y, a.y);
        a.z = fmaf(qv[d4].z, k0v.z, a.z);
        a.w = fmaf(qv[d4].w, k0v.w, a.w);
        c.x = fmaf(qv[d4 + 1].x, k1v.x, c.x);
        c.y = fmaf(qv[d4 + 1].y, k1v.y, c.y);
        c.z = fmaf(qv[d4 + 1].z, k1v.z, c.z);
        c.w = fmaf(qv[d4 + 1].w, k1v.w, c.w);
      }
      float s = (((a.x + a.y) + (a.z + a.w)) + ((c.x + c.y) + (c.z + c.w))) * SCALE;
      float e = act ? __expf(s) : 0.f;
      if (act) els[lane * 33 + j] = e;
      l_acc += e;
    }
    __syncthreads();

    // phase 2: P*V for all 32 keys, this wave's 16 dims; lane = query
    if (act) {
      const float4* vbase = &vt[w * 4];
#pragma unroll 4
      for (int j = 0; j < 32; ++j) {
        float e = els[lane * 33 + j];
        const float4* vrow = vbase + j * 16;
        float4 v0 = vrow[0], v1 = vrow[1], v2 = vrow[2], v3 = vrow[3];
        o4[0].x = fmaf(e, v0.x, o4[0].x); o4[0].y = fmaf(e, v0.y, o4[0].y);
        o4[0].z = fmaf(e, v0.z, o4[0].z); o4[0].w = fmaf(e, v0.w, o4[0].w);
        o4[1].x = fmaf(e, v1.x, o4[1].x); o4[1].y = fmaf(e, v1.y, o4[1].y);
        o4[1].z = fmaf(e, v1.z, o4[1].z); o4[1].w = fmaf(e, v1.w, o4[1].w);
        o4[2].x = fmaf(e, v2.x, o4[2].x); o4[2].y = fmaf(e, v2.y, o4[2].y);
        o4[2].z = fmaf(e, v2.z, o4[2].z); o4[2].w = fmaf(e, v2.w, o4[2].w);
        o4[3].x = fmaf(e, v3.x, o4[3].x); o4[3].y = fmaf(e, v3.y, o4[3].y);
        o4[3].z = fmaf(e, v3.z, o4[3].z); o4[3].w = fmaf(e, v3.w, o4[3].w);
      }
    }

    // dump unnormalized weights (coalesced-ish 128B runs)
    for (int i = t; i < UU * 32; i += 256) {
      int u2 = i >> 5, j2 = i & 31;
      wout[((size_t)(bh * UU + u2)) * LQ + k0 + j2] = els[u2 * 33 + j2];
    }
  }

  if (act) {
    atomicAdd(&l3[bh * UU + lane], l_acc);
    float* ap = acc + ((size_t)(bh * UU + lane)) * DH + w * 16;
#pragma unroll
    for (int i = 0; i < 4; ++i) {
      atomicAdd(ap + i * 4 + 0, o4[i].x);
      atomicAdd(ap + i * 4 + 1, o4[i].y);
      atomicAdd(ap + i * 4 + 2, o4[i].z);
      atomicAdd(ap + i * 4 + 3, o4[i].w);
    }
  }
}

// ---------------------------------------------------------------------------
// Kernel 4: normalize weights; scatter normalized P*V into zeroed output.
// ---------------------------------------------------------------------------
__global__ __launch_bounds__(256) void finalize_kernel(const int* __restrict__ sel,
                                                       const float* __restrict__ l3,
                                                       const float* __restrict__ acc,
                                                       float* __restrict__ out,
                                                       float* __restrict__ wout) {
  const int N1 = NBH * UU * LQ;
  const int N2 = NBH * UU * DH;
  int i = blockIdx.x * 256 + threadIdx.x;
  if (i < N1) {
    int bhu = i >> 11;
    wout[i] = wout[i] / l3[bhu];
  } else {
    int i2 = i - N1;
    if (i2 < N2) {
      int bhu = i2 >> 6, d = i2 & 63;
      int bh = bhu / UU;
      int b = bh >> 4, h = bh & 15;
      int q = sel[bhu];
      out[((size_t)(b * LQ + q)) * DM + h * DH + d] = acc[i2] / l3[bhu];
    }
  }
}

extern "C" void kernel_launch(void* const* d_in, const int* in_sizes, int n_in,
                              void* d_out, int out_size, void* d_ws, size_t ws_size,
                              hipStream_t stream) {
  (void)in_sizes; (void)n_in; (void)ws_size;
  const float* Q = (const float*)d_in[0];
  const float* K = (const float*)d_in[1];
  const float* V = (const float*)d_in[2];
  float* out = (float*)d_out;
  float* wout = out + (size_t)4 * LQ * DM;
  double* vals = (double*)d_ws;
  int* sel = (int*)((char*)d_ws + 1048576);
  float* l3 = (float*)((char*)d_ws + 1048576 + 9728);
  float* acc = (float*)((char*)d_ws + 1048576 + 19456);

  hipMemsetAsync(out, 0, (size_t)4 * LQ * DM * sizeof(float), stream);
  hipMemsetAsync(d_ws, 0, (size_t)WS_BYTES, stream);

  kl_mfma<<<1024, 256, 0, stream>>>(Q, K, vals);
  topk_kernel<<<NBH, 256, 0, stream>>>(vals, sel);
  attn_kernel<<<NBH * 16, 256, 0, stream>>>(Q, K, V, sel, wout, l3, acc);
  finalize_kernel<<<(NBH * UU * LQ + NBH * UU * DH + 255) / 256, 256, 0, stream>>>(
      sel, l3, acc, out, wout);
}

// Round 5
// 482.462 us; speedup vs baseline: 1.1792x; 1.1792x over previous
//
#include <hip/hip_runtime.h>
#include <math.h>

#define LQ 2048
#define DM 1024
#define NH 16
#define DH 64
#define UU 38
#define NBH 64            // B*NH = 4*16
#define SCALE 0.125f      // 1/sqrt(64)

typedef _Float16 f16x8 __attribute__((ext_vector_type(8)));
typedef _Float16 f16x4 __attribute__((ext_vector_type(4)));
typedef float f32x4 __attribute__((ext_vector_type(4)));

// workspace layout (bytes) — all regions fully written before read, NO
// pre-zeroing needed (no atomics anywhere):
//   [0, 1048576)            vals  : 131072 f64 (KL per query)
//   [1048576, +9728)        sel   : 64*38 int
//   [1058304, +9728)        l3    : 64*38 f32 (softmax denominators)
//   [1068032, +155648)      lpart : [64][16][38] f32 (denominator partials)
//   [1223680, +2490368)     opart : [64][4][38][64] f32 (P*V partials)
#define OFF_SEL   1048576
#define OFF_L3    1058304
#define OFF_LPART 1068032
#define OFF_OPART 1223680

// ---------------------------------------------------------------------------
// Kernel 1: KL via fp16-split MFMA (unchanged; verified rounds 3-4).
// ---------------------------------------------------------------------------
__global__ __launch_bounds__(256) void kl_mfma(const float* __restrict__ Q,
                                               const float* __restrict__ K,
                                               double* __restrict__ vals) {
  int bh = blockIdx.x & 63;
  int qc = blockIdx.x >> 6;
  int b = bh >> 4, h = bh & 15;
  int t = threadIdx.x;
  int lane = t & 63, w = t >> 6;
  int quad = lane >> 4, l15 = lane & 15;

  __shared__ __align__(16) char smem[34816];
  float* qs = (float*)smem;

#pragma unroll
  for (int i = 0; i < 8; ++i) {
    int idx = i * 256 + t;
    int row = idx >> 4, d4 = idx & 15;
    float4 v = *(const float4*)(Q + ((size_t)(b * LQ + qc * 128 + row)) * DM + h * DH + d4 * 4);
    *(float4*)(qs + row * 68 + d4 * 4) = v;
  }
  __syncthreads();

  f16x8 ahi[2][2], alo[2][2];
#pragma unroll
  for (int qt = 0; qt < 2; ++qt)
#pragma unroll
    for (int c = 0; c < 2; ++c) {
      const float* p = qs + (w * 32 + qt * 16 + l15) * 68 + c * 32 + quad * 8;
      f16x8 hi, lo;
#pragma unroll
      for (int j = 0; j < 8; ++j) {
        float x = p[j];
        _Float16 hh = (_Float16)x;
        hi[j] = hh;
        lo[j] = (_Float16)(x - (float)hh);
      }
      ahi[qt][c] = hi;
      alo[qt][c] = lo;
    }
  __syncthreads();

  _Float16* khi = (_Float16*)smem;        // [64][88]
  _Float16* klo = khi + 64 * 88;

  double l64[2][4], t64[2][4];
#pragma unroll
  for (int qt = 0; qt < 2; ++qt)
#pragma unroll
    for (int r = 0; r < 4; ++r) { l64[qt][r] = 0.0; t64[qt][r] = 0.0; }

  for (int kb = 0; kb < LQ; kb += 64) {
    __syncthreads();
#pragma unroll
    for (int i = 0; i < 4; ++i) {
      int idx = i * 256 + t;
      int key = idx >> 4, d4 = idx & 15;
      float4 v = *(const float4*)(K + ((size_t)(b * LQ + kb + key)) * DM + h * DH + d4 * 4);
      f16x4 hv, lv;
      hv[0] = (_Float16)v.x; lv[0] = (_Float16)(v.x - (float)hv[0]);
      hv[1] = (_Float16)v.y; lv[1] = (_Float16)(v.y - (float)hv[1]);
      hv[2] = (_Float16)v.z; lv[2] = (_Float16)(v.z - (float)hv[2]);
      hv[3] = (_Float16)v.w; lv[3] = (_Float16)(v.w - (float)hv[3]);
      *(f16x4*)(khi + key * 88 + d4 * 4) = hv;
      *(f16x4*)(klo + key * 88 + d4 * 4) = lv;
    }
    __syncthreads();

    float l32[2][4], t32[2][4];
#pragma unroll
    for (int qt = 0; qt < 2; ++qt)
#pragma unroll
      for (int r = 0; r < 4; ++r) { l32[qt][r] = 0.f; t32[qt][r] = 0.f; }

#pragma unroll
    for (int kt = 0; kt < 4; ++kt) {
      const _Float16* bp = khi + (kt * 16 + l15) * 88 + quad * 8;
      const _Float16* bp2 = klo + (kt * 16 + l15) * 88 + quad * 8;
      f16x8 bhi0 = *(const f16x8*)bp;
      f16x8 bhi1 = *(const f16x8*)(bp + 32);
      f16x8 blo0 = *(const f16x8*)bp2;
      f16x8 blo1 = *(const f16x8*)(bp2 + 32);
#pragma unroll
      for (int qt = 0; qt < 2; ++qt) {
        f32x4 cacc = {0.f, 0.f, 0.f, 0.f};
        cacc = __builtin_amdgcn_mfma_f32_16x16x32_f16(alo[qt][0], bhi0, cacc, 0, 0, 0);
        cacc = __builtin_amdgcn_mfma_f32_16x16x32_f16(alo[qt][1], bhi1, cacc, 0, 0, 0);
        cacc = __builtin_amdgcn_mfma_f32_16x16x32_f16(ahi[qt][0], blo0, cacc, 0, 0, 0);
        cacc = __builtin_amdgcn_mfma_f32_16x16x32_f16(ahi[qt][1], blo1, cacc, 0, 0, 0);
        cacc = __builtin_amdgcn_mfma_f32_16x16x32_f16(ahi[qt][0], bhi0, cacc, 0, 0, 0);
        cacc = __builtin_amdgcn_mfma_f32_16x16x32_f16(ahi[qt][1], bhi1, cacc, 0, 0, 0);
#pragma unroll
        for (int r = 0; r < 4; ++r) {
          float s = cacc[r] * SCALE;
          float e = __expf(s);
          l32[qt][r] += e;
          t32[qt][r] = fmaf(s, e, t32[qt][r]);
        }
      }
    }
#pragma unroll
    for (int qt = 0; qt < 2; ++qt)
#pragma unroll
      for (int r = 0; r < 4; ++r) {
        l64[qt][r] += (double)l32[qt][r];
        t64[qt][r] += (double)t32[qt][r];
      }
  }

#pragma unroll
  for (int qt = 0; qt < 2; ++qt)
#pragma unroll
    for (int r = 0; r < 4; ++r) {
      double lv = l64[qt][r], tv = t64[qt][r];
#pragma unroll
      for (int m = 1; m < 16; m <<= 1) {
        lv += __shfl_xor(lv, m);
        tv += __shfl_xor(tv, m);
      }
      if (l15 == 0) {
        int qg = qc * 128 + w * 32 + qt * 16 + quad * 4 + r;
        vals[(size_t)bh * LQ + qg] = tv / lv - log(lv) + 7.624618986159398;
      }
    }
}

// ---------------------------------------------------------------------------
// Kernel 2: per-(b,h) top-38, 1024 threads (2 elems/thread). 38 serial
// extractions, each: per-thread 2-candidate max -> 64-lane shfl reduce ->
// 16-wave LDS reduce. Ties -> lower index (matches lax.top_k stable order).
// ---------------------------------------------------------------------------
__global__ __launch_bounds__(1024) void topk_kernel(const double* __restrict__ vals_in,
                                                    int* __restrict__ idxout) {
  int bh = blockIdx.x;
  int t = threadIdx.x;
  int w = t >> 6;
  __shared__ double vals[LQ];
  __shared__ double bv[16];
  __shared__ int bi[16];
  vals[t] = vals_in[(size_t)bh * LQ + t];
  vals[t + 1024] = vals_in[(size_t)bh * LQ + t + 1024];
  __syncthreads();
  for (int u = 0; u < UU; ++u) {
    double v0 = vals[t], v1 = vals[t + 1024];
    double best = v0; int besti = t;
    if (v1 > best) { best = v1; besti = t + 1024; }
#pragma unroll
    for (int off = 32; off > 0; off >>= 1) {
      double ov = __shfl_down(best, off);
      int oi = __shfl_down(besti, off);
      if (ov > best || (ov == best && oi < besti)) { best = ov; besti = oi; }
    }
    if ((t & 63) == 0) { bv[w] = best; bi[w] = besti; }
    __syncthreads();
    if (t == 0) {
      double fb = bv[0]; int fi = bi[0];
      for (int w2 = 1; w2 < 16; ++w2) {
        if (bv[w2] > fb || (bv[w2] == fb && bi[w2] < fi)) { fb = bv[w2]; fi = bi[w2]; }
      }
      idxout[bh * UU + u] = fi;
      vals[fi] = -INFINITY;
    }
    __syncthreads();
  }
}

// ---------------------------------------------------------------------------
// Kernel 3a: weights. grid = 64 bh x 16 key-splits, 128 keys/block in 2
// tiles of 64. lane = query (38 active); wave handles 16 keys/tile. e^s ->
// els (stride 65: (lane+j)%32 banks, conflict-free) -> coalesced wout dump.
// Denominator partials: per-wave l_acc summed in fixed wave order -> lpart
// (owner-written, NO atomics). LDS ~37 KB -> 4 blocks/CU.
// ---------------------------------------------------------------------------
__global__ __launch_bounds__(256) void attn_w(const float* __restrict__ Q,
                                              const float* __restrict__ K,
                                              const int* __restrict__ sel,
                                              float* __restrict__ wout,
                                              float* __restrict__ lpart) {
  int bh = blockIdx.x >> 4;
  int ks = blockIdx.x & 15;
  int b = bh >> 4, h = bh & 15;
  int t = threadIdx.x;
  int lane = t & 63, w = t >> 6;

  __shared__ float qs[UU * 68];     // 10.3 KB
  __shared__ float4 kt[64 * 16];    // 16 KB
  __shared__ float els[UU * 65];    // 9.9 KB
  __shared__ float lw[4][UU];
  __shared__ int sidx[UU];

  if (t < UU) sidx[t] = sel[bh * UU + t];
  __syncthreads();
  for (int i = t; i < UU * 16; i += 256) {
    int u = i >> 4, d4 = i & 15;
    *(float4*)(qs + u * 68 + d4 * 4) =
        *(const float4*)(Q + ((size_t)(b * LQ + sidx[u])) * DM + h * DH + d4 * 4);
  }
  __syncthreads();

  bool act = lane < UU;
  float4 qv[16];
  if (act) {
    const float4* qp = (const float4*)(qs + lane * 68);
#pragma unroll
    for (int i = 0; i < 16; ++i) qv[i] = qp[i];
  } else {
#pragma unroll
    for (int i = 0; i < 16; ++i) qv[i] = make_float4(0.f, 0.f, 0.f, 0.f);
  }

  float l_acc = 0.f;

  for (int tile = 0; tile < 2; ++tile) {
    int k0 = ks * 128 + tile * 64;
    __syncthreads();   // prev dump done before restaging kt
#pragma unroll
    for (int i = 0; i < 4; ++i) {
      int idx = i * 256 + t;
      int kk = idx >> 4, d4 = idx & 15;
      kt[idx] = ((const float4*)(K + ((size_t)(b * LQ + k0 + kk)) * DM + h * DH))[d4];
    }
    __syncthreads();

#pragma unroll
    for (int jj = 0; jj < 16; ++jj) {
      int j = w * 16 + jj;
      const float4* krow = &kt[j * 16];
      float4 a = make_float4(0.f, 0.f, 0.f, 0.f);
      float4 c = make_float4(0.f, 0.f, 0.f, 0.f);
#pragma unroll
      for (int d4 = 0; d4 < 16; d4 += 2) {
        float4 k0v = krow[d4];
        float4 k1v = krow[d4 + 1];
        a.x = fmaf(qv[d4].x, k0v.x, a.x);
        a.y = fmaf(qv[d4].y, k0v.y, a.y);
        a.z = fmaf(qv[d4].z, k0v.z, a.z);
        a.w = fmaf(qv[d4].w, k0v.w, a.w);
        c.x = fmaf(qv[d4 + 1].x, k1v.x, c.x);
        c.y = fmaf(qv[d4 + 1].y, k1v.y, c.y);
        c.z = fmaf(qv[d4 + 1].z, k1v.z, c.z);
        c.w = fmaf(qv[d4 + 1].w, k1v.w, c.w);
      }
      float s = (((a.x + a.y) + (a.z + a.w)) + ((c.x + c.y) + (c.z + c.w))) * SCALE;
      float e = act ? __expf(s) : 0.f;
      if (act) els[lane * 65 + j] = e;
      l_acc += e;
    }
    __syncthreads();

    // coalesced dump: consecutive threads -> consecutive keys (256 B runs)
    for (int i = t; i < UU * 64; i += 256) {
      int u2 = i >> 6, j2 = i & 63;
      wout[((size_t)(bh * UU + u2)) * LQ + k0 + j2] = els[u2 * 65 + j2];
    }
  }

  if (act) lw[w][lane] = l_acc;
  __syncthreads();
  if (t < UU)
    lpart[(bh * 16 + ks) * UU + t] = ((lw[0][t] + lw[1][t]) + (lw[2][t] + lw[3][t]));
}

// ---------------------------------------------------------------------------
// Kernel 3b: P*V partials. grid = 64 bh x 4 key-splits of 512. Thread (ug =
// t>>6, d = t&63) accumulates O[u=ug+4p][d] for p<10 over its keys. V read
// coalesced (256 B/row); P chunk staged in LDS, broadcast-read. opart
// owner-written, no atomics. ks==0 block also reduces lpart -> l3.
// ---------------------------------------------------------------------------
__global__ __launch_bounds__(256) void attn_pv(const float* __restrict__ V,
                                               const float* __restrict__ wout,
                                               const float* __restrict__ lpart,
                                               float* __restrict__ opart,
                                               float* __restrict__ l3) {
  int bh = blockIdx.x >> 2;
  int ks = blockIdx.x & 3;
  int b = bh >> 4, h = bh & 15;
  int t = threadIdx.x;
  int d = t & 63, ug = t >> 6;

  if (ks == 0 && t < UU) {
    float s = 0.f;
#pragma unroll
    for (int i = 0; i < 16; ++i) s += lpart[(bh * 16 + i) * UU + t];
    l3[bh * UU + t] = s;
  }

  __shared__ float ps[40 * 132];   // 21.1 KB; rows 38,39 are padding
  float o[10];
#pragma unroll
  for (int p = 0; p < 10; ++p) o[p] = 0.f;

  for (int chunk = 0; chunk < 4; ++chunk) {
    int c0 = ks * 512 + chunk * 128;
    __syncthreads();
    for (int i = t; i < UU * 32; i += 256) {
      int u = i >> 5, d4 = i & 31;
      *(float4*)(ps + u * 132 + d4 * 4) =
          *(const float4*)(wout + ((size_t)(bh * UU + u)) * LQ + c0 + d4 * 4);
    }
    __syncthreads();
#pragma unroll 4
    for (int j = 0; j < 128; ++j) {
      float vj = V[((size_t)(b * LQ + c0 + j)) * DM + h * DH + d];
#pragma unroll
      for (int p = 0; p < 10; ++p) {
        o[p] = fmaf(ps[(ug + 4 * p) * 132 + j], vj, o[p]);
      }
    }
  }

#pragma unroll
  for (int p = 0; p < 10; ++p) {
    int u = ug + 4 * p;
    if (u < UU) opart[((size_t)((bh * 4 + ks) * UU + u)) * DH + d] = o[p];
  }
}

// ---------------------------------------------------------------------------
// Kernel 4: normalize weights; reduce opart (fixed order) + scatter into the
// (pre-zeroed) dense output.
// ---------------------------------------------------------------------------
__global__ __launch_bounds__(256) void finalize_kernel(const int* __restrict__ sel,
                                                       const float* __restrict__ l3,
                                                       const float* __restrict__ opart,
                                                       float* __restrict__ out,
                                                       float* __restrict__ wout) {
  const int N1 = NBH * UU * LQ;
  const int N2 = NBH * UU * DH;
  int i = blockIdx.x * 256 + threadIdx.x;
  if (i < N1) {
    int bhu = i >> 11;
    wout[i] = wout[i] / l3[bhu];
  } else {
    int i2 = i - N1;
    if (i2 < N2) {
      int bhu = i2 >> 6, d = i2 & 63;
      int bh = bhu / UU;
      int u = bhu - bh * UU;
      int b = bh >> 4, h = bh & 15;
      float s = 0.f;
#pragma unroll
      for (int p = 0; p < 4; ++p)
        s += opart[((size_t)((bh * 4 + p) * UU + u)) * DH + d];
      out[((size_t)(b * LQ + sel[bhu])) * DM + h * DH + d] = s / l3[bhu];
    }
  }
}

extern "C" void kernel_launch(void* const* d_in, const int* in_sizes, int n_in,
                              void* d_out, int out_size, void* d_ws, size_t ws_size,
                              hipStream_t stream) {
  (void)in_sizes; (void)n_in; (void)ws_size;
  const float* Q = (const float*)d_in[0];
  const float* K = (const float*)d_in[1];
  const float* V = (const float*)d_in[2];
  float* out = (float*)d_out;
  float* wout = out + (size_t)4 * LQ * DM;
  double* vals = (double*)d_ws;
  int* sel = (int*)((char*)d_ws + OFF_SEL);
  float* l3 = (float*)((char*)d_ws + OFF_L3);
  float* lpart = (float*)((char*)d_ws + OFF_LPART);
  float* opart = (float*)((char*)d_ws + OFF_OPART);

  // zero only the dense-output scatter target
  hipMemsetAsync(out, 0, (size_t)4 * LQ * DM * sizeof(float), stream);

  kl_mfma<<<1024, 256, 0, stream>>>(Q, K, vals);
  topk_kernel<<<NBH, 1024, 0, stream>>>(vals, sel);
  attn_w<<<NBH * 16, 256, 0, stream>>>(Q, K, sel, wout, lpart);
  attn_pv<<<NBH * 4, 256, 0, stream>>>(V, wout, lpart, opart, l3);
  finalize_kernel<<<(NBH * UU * LQ + NBH * UU * DH + 255) / 256, 256, 0, stream>>>(
      sel, l3, opart, out, wout);
}

// Round 6
// 438.724 us; speedup vs baseline: 1.2968x; 1.0997x over previous
//
#include <hip/hip_runtime.h>
#include <math.h>

#define LQ 2048
#define DM 1024
#define NH 16
#define DH 64
#define UU 38
#define NBH 64            // B*NH = 4*16
#define SCALE 0.125f      // 1/sqrt(64)

typedef _Float16 f16x8 __attribute__((ext_vector_type(8)));
typedef float f32x4 __attribute__((ext_vector_type(4)));

// workspace layout (bytes) — unchanged from round 5 (known to fit ws_size):
//   [0, 1048576)            vals  : 131072 f64 (KL per query)
//   [1048576, +9728)        sel   : 64*38 int
//   [1058304, +9728)        l3    : 64*38 f32
//   [1068032, +155648)      lpart : [64][16][38] f32
//   [1223680, +2490368)     opart : [64][4][38][64] f32
#define OFF_SEL   1048576
#define OFF_L3    1058304
#define OFF_LPART 1068032
#define OFF_OPART 1223680

// ---------------------------------------------------------------------------
// Kernel 1: KL via fp16-split MFMA, round-6 rewrite:
//  - K LDS layout: stride 64 halves + XOR-swizzle (blk ^ (key&7)) -> all-32-
//    bank uniform on staging writes AND B-frag reads (kills the 8.5M
//    SQ_LDS_BANK_CONFLICT of the stride-88 layout, which hit even banks only).
//  - Register prefetch pipeline: chunk k+1's global loads issue during chunk
//    k's compute; convert->LDS at loop top. Same 2 barriers/chunk.
//  - Epilogue: e = exp2(r*C1) with C1 = SCALE*log2e; accumulate l += e,
//    t' += r*e; KL = SCALE*(t'/l) - log(l) + logL. One fewer VALU/element,
//    numerically equivalent to __expf(r*SCALE).
// ---------------------------------------------------------------------------
__global__ __launch_bounds__(256) void kl_mfma(const float* __restrict__ Q,
                                               const float* __restrict__ K,
                                               double* __restrict__ vals) {
  int bh = blockIdx.x & 63;
  int qc = blockIdx.x >> 6;
  int b = bh >> 4, h = bh & 15;
  int t = threadIdx.x;
  int lane = t & 63, w = t >> 6;
  int quad = lane >> 4, l15 = lane & 15;

  __shared__ __align__(16) char smem[34816];   // qs (34816B) unioned with khi/klo (16KB)
  float* qs = (float*)smem;

  const float* kbase = K + ((size_t)b * LQ) * DM + h * DH;

  // prefetch slots: thread t, slot s -> (key = s*32 + t/8, blk = t%8)
  int pkey0 = (t >> 3), pkey1 = 32 + (t >> 3);
  int pblk = t & 7;
  float4 pf00, pf01, pf10, pf11;
  {
    const float* s0 = kbase + (size_t)pkey0 * DM + pblk * 8;
    const float* s1 = kbase + (size_t)pkey1 * DM + pblk * 8;
    pf00 = *(const float4*)s0; pf01 = *(const float4*)(s0 + 4);
    pf10 = *(const float4*)s1; pf11 = *(const float4*)(s1 + 4);
  }

  // stage Q (fp32, stride 68 -> conflict-light, one-time)
#pragma unroll
  for (int i = 0; i < 8; ++i) {
    int idx = i * 256 + t;
    int row = idx >> 4, d4 = idx & 15;
    float4 v = *(const float4*)(Q + ((size_t)(b * LQ + qc * 128 + row)) * DM + h * DH + d4 * 4);
    *(float4*)(qs + row * 68 + d4 * 4) = v;
  }
  __syncthreads();

  f16x8 ahi[2][2], alo[2][2];
#pragma unroll
  for (int qt = 0; qt < 2; ++qt)
#pragma unroll
    for (int c = 0; c < 2; ++c) {
      const float* p = qs + (w * 32 + qt * 16 + l15) * 68 + c * 32 + quad * 8;
      f16x8 hi, lo;
#pragma unroll
      for (int j = 0; j < 8; ++j) {
        float x = p[j];
        _Float16 hh = (_Float16)x;
        hi[j] = hh;
        lo[j] = (_Float16)(x - (float)hh);
      }
      ahi[qt][c] = hi;
      alo[qt][c] = lo;
    }
  __syncthreads();   // frag reads done; khi/klo may now overwrite qs

  _Float16* khi = (_Float16*)smem;        // [64 keys][64 halves], XOR-swizzled blocks
  _Float16* klo = khi + 64 * 64;

  int swb0 = pblk ^ (pkey0 & 7);
  int swb1 = pblk ^ (pkey1 & 7);
  int bsw0 = quad ^ (l15 & 7);            // B-frag swizzled blocks (c=0 / c=1)
  int bsw1 = (quad + 4) ^ (l15 & 7);

  const float C1 = 0.18033688011112042f;  // SCALE * log2(e)

  double l64[2][4], t64[2][4];
#pragma unroll
  for (int qt = 0; qt < 2; ++qt)
#pragma unroll
    for (int r = 0; r < 4; ++r) { l64[qt][r] = 0.0; t64[qt][r] = 0.0; }

  for (int kb = 0; kb < LQ; kb += 64) {
    // convert prefetched regs -> swizzled LDS
    {
      f16x8 hi, lo;
#define CV(i, xx) { float x_ = (xx); _Float16 hh = (_Float16)x_; hi[i] = hh; lo[i] = (_Float16)(x_ - (float)hh); }
      CV(0, pf00.x) CV(1, pf00.y) CV(2, pf00.z) CV(3, pf00.w)
      CV(4, pf01.x) CV(5, pf01.y) CV(6, pf01.z) CV(7, pf01.w)
      *(f16x8*)(khi + pkey0 * 64 + swb0 * 8) = hi;
      *(f16x8*)(klo + pkey0 * 64 + swb0 * 8) = lo;
      CV(0, pf10.x) CV(1, pf10.y) CV(2, pf10.z) CV(3, pf10.w)
      CV(4, pf11.x) CV(5, pf11.y) CV(6, pf11.z) CV(7, pf11.w)
      *(f16x8*)(khi + pkey1 * 64 + swb1 * 8) = hi;
      *(f16x8*)(klo + pkey1 * 64 + swb1 * 8) = lo;
#undef CV
    }
    __syncthreads();

    // prefetch next chunk (lands during compute below)
    if (kb + 64 < LQ) {
      const float* s0 = kbase + (size_t)(kb + 64 + pkey0) * DM + pblk * 8;
      const float* s1 = kbase + (size_t)(kb + 64 + pkey1) * DM + pblk * 8;
      pf00 = *(const float4*)s0; pf01 = *(const float4*)(s0 + 4);
      pf10 = *(const float4*)s1; pf11 = *(const float4*)(s1 + 4);
    }

    float l32[2][4], t32[2][4];
#pragma unroll
    for (int qt = 0; qt < 2; ++qt)
#pragma unroll
      for (int r = 0; r < 4; ++r) { l32[qt][r] = 0.f; t32[qt][r] = 0.f; }

#pragma unroll
    for (int kt = 0; kt < 4; ++kt) {
      int key = kt * 16 + l15;
      f16x8 bhi0 = *(const f16x8*)(khi + key * 64 + bsw0 * 8);
      f16x8 bhi1 = *(const f16x8*)(khi + key * 64 + bsw1 * 8);
      f16x8 blo0 = *(const f16x8*)(klo + key * 64 + bsw0 * 8);
      f16x8 blo1 = *(const f16x8*)(klo + key * 64 + bsw1 * 8);
#pragma unroll
      for (int qt = 0; qt < 2; ++qt) {
        f32x4 cacc = {0.f, 0.f, 0.f, 0.f};
        cacc = __builtin_amdgcn_mfma_f32_16x16x32_f16(alo[qt][0], bhi0, cacc, 0, 0, 0);
        cacc = __builtin_amdgcn_mfma_f32_16x16x32_f16(alo[qt][1], bhi1, cacc, 0, 0, 0);
        cacc = __builtin_amdgcn_mfma_f32_16x16x32_f16(ahi[qt][0], blo0, cacc, 0, 0, 0);
        cacc = __builtin_amdgcn_mfma_f32_16x16x32_f16(ahi[qt][1], blo1, cacc, 0, 0, 0);
        cacc = __builtin_amdgcn_mfma_f32_16x16x32_f16(ahi[qt][0], bhi0, cacc, 0, 0, 0);
        cacc = __builtin_amdgcn_mfma_f32_16x16x32_f16(ahi[qt][1], bhi1, cacc, 0, 0, 0);
#pragma unroll
        for (int r = 0; r < 4; ++r) {
          float rr = cacc[r];
          float e = exp2f(rr * C1);        // e^(rr*SCALE)
          l32[qt][r] += e;
          t32[qt][r] = fmaf(rr, e, t32[qt][r]);
        }
      }
    }
#pragma unroll
    for (int qt = 0; qt < 2; ++qt)
#pragma unroll
      for (int r = 0; r < 4; ++r) {
        l64[qt][r] += (double)l32[qt][r];
        t64[qt][r] += (double)t32[qt][r];
      }
    __syncthreads();   // compute reads done -> next convert may overwrite
  }

#pragma unroll
  for (int qt = 0; qt < 2; ++qt)
#pragma unroll
    for (int r = 0; r < 4; ++r) {
      double lv = l64[qt][r], tv = t64[qt][r];
#pragma unroll
      for (int m = 1; m < 16; m <<= 1) {
        lv += __shfl_xor(lv, m);
        tv += __shfl_xor(tv, m);
      }
      if (l15 == 0) {
        int qg = qc * 128 + w * 32 + qt * 16 + quad * 4 + r;
        vals[(size_t)bh * LQ + qg] = 0.125 * (tv / lv) - log(lv) + 7.624618986159398;
      }
    }
}

// ---------------------------------------------------------------------------
// Kernel 2: per-(b,h) top-38 by KL (fp64), descending, ties -> lower index.
// (unchanged, validated)
// ---------------------------------------------------------------------------
__global__ __launch_bounds__(1024) void topk_kernel(const double* __restrict__ vals_in,
                                                    int* __restrict__ idxout) {
  int bh = blockIdx.x;
  int t = threadIdx.x;
  int w = t >> 6;
  __shared__ double vals[LQ];
  __shared__ double bv[16];
  __shared__ int bi[16];
  vals[t] = vals_in[(size_t)bh * LQ + t];
  vals[t + 1024] = vals_in[(size_t)bh * LQ + t + 1024];
  __syncthreads();
  for (int u = 0; u < UU; ++u) {
    double v0 = vals[t], v1 = vals[t + 1024];
    double best = v0; int besti = t;
    if (v1 > best) { best = v1; besti = t + 1024; }
#pragma unroll
    for (int off = 32; off > 0; off >>= 1) {
      double ov = __shfl_down(best, off);
      int oi = __shfl_down(besti, off);
      if (ov > best || (ov == best && oi < besti)) { best = ov; besti = oi; }
    }
    if ((t & 63) == 0) { bv[w] = best; bi[w] = besti; }
    __syncthreads();
    if (t == 0) {
      double fb = bv[0]; int fi = bi[0];
      for (int w2 = 1; w2 < 16; ++w2) {
        if (bv[w2] > fb || (bv[w2] == fb && bi[w2] < fi)) { fb = bv[w2]; fi = bi[w2]; }
      }
      idxout[bh * UU + u] = fi;
      vals[fi] = -INFINITY;
    }
    __syncthreads();
  }
}

// ---------------------------------------------------------------------------
// Kernel 3a: weights (unchanged from round 5, validated).
// ---------------------------------------------------------------------------
__global__ __launch_bounds__(256) void attn_w(const float* __restrict__ Q,
                                              const float* __restrict__ K,
                                              const int* __restrict__ sel,
                                              float* __restrict__ wout,
                                              float* __restrict__ lpart) {
  int bh = blockIdx.x >> 4;
  int ks = blockIdx.x & 15;
  int b = bh >> 4, h = bh & 15;
  int t = threadIdx.x;
  int lane = t & 63, w = t >> 6;

  __shared__ float qs[UU * 68];
  __shared__ float4 kt[64 * 16];
  __shared__ float els[UU * 65];
  __shared__ float lw[4][UU];
  __shared__ int sidx[UU];

  if (t < UU) sidx[t] = sel[bh * UU + t];
  __syncthreads();
  for (int i = t; i < UU * 16; i += 256) {
    int u = i >> 4, d4 = i & 15;
    *(float4*)(qs + u * 68 + d4 * 4) =
        *(const float4*)(Q + ((size_t)(b * LQ + sidx[u])) * DM + h * DH + d4 * 4);
  }
  __syncthreads();

  bool act = lane < UU;
  float4 qv[16];
  if (act) {
    const float4* qp = (const float4*)(qs + lane * 68);
#pragma unroll
    for (int i = 0; i < 16; ++i) qv[i] = qp[i];
  } else {
#pragma unroll
    for (int i = 0; i < 16; ++i) qv[i] = make_float4(0.f, 0.f, 0.f, 0.f);
  }

  float l_acc = 0.f;

  for (int tile = 0; tile < 2; ++tile) {
    int k0 = ks * 128 + tile * 64;
    __syncthreads();
#pragma unroll
    for (int i = 0; i < 4; ++i) {
      int idx = i * 256 + t;
      int kk = idx >> 4, d4 = idx & 15;
      kt[idx] = ((const float4*)(K + ((size_t)(b * LQ + k0 + kk)) * DM + h * DH))[d4];
    }
    __syncthreads();

#pragma unroll
    for (int jj = 0; jj < 16; ++jj) {
      int j = w * 16 + jj;
      const float4* krow = &kt[j * 16];
      float4 a = make_float4(0.f, 0.f, 0.f, 0.f);
      float4 c = make_float4(0.f, 0.f, 0.f, 0.f);
#pragma unroll
      for (int d4 = 0; d4 < 16; d4 += 2) {
        float4 k0v = krow[d4];
        float4 k1v = krow[d4 + 1];
        a.x = fmaf(qv[d4].x, k0v.x, a.x);
        a.y = fmaf(qv[d4].y, k0v.y, a.y);
        a.z = fmaf(qv[d4].z, k0v.z, a.z);
        a.w = fmaf(qv[d4].w, k0v.w, a.w);
        c.x = fmaf(qv[d4 + 1].x, k1v.x, c.x);
        c.y = fmaf(qv[d4 + 1].y, k1v.y, c.y);
        c.z = fmaf(qv[d4 + 1].z, k1v.z, c.z);
        c.w = fmaf(qv[d4 + 1].w, k1v.w, c.w);
      }
      float s = (((a.x + a.y) + (a.z + a.w)) + ((c.x + c.y) + (c.z + c.w))) * SCALE;
      float e = act ? __expf(s) : 0.f;
      if (act) els[lane * 65 + j] = e;
      l_acc += e;
    }
    __syncthreads();

    for (int i = t; i < UU * 64; i += 256) {
      int u2 = i >> 6, j2 = i & 63;
      wout[((size_t)(bh * UU + u2)) * LQ + k0 + j2] = els[u2 * 65 + j2];
    }
  }

  if (act) lw[w][lane] = l_acc;
  __syncthreads();
  if (t < UU)
    lpart[(bh * 16 + ks) * UU + t] = ((lw[0][t] + lw[1][t]) + (lw[2][t] + lw[3][t]));
}

// ---------------------------------------------------------------------------
// Kernel 3b: P*V partials, round-6: 1024 threads (16 waves/block), V staged
// in LDS (stride 68: 16B-aligned, 2-way-free banks), P rows read as
// wave-uniform float4 broadcasts. Thread (ug=t>>6, d=t&63) owns u = ug,
// ug+16, ug+32(<38). opart owner-written, no atomics; same layout as r5.
// ---------------------------------------------------------------------------
__global__ __launch_bounds__(1024) void attn_pv(const float* __restrict__ V,
                                                const float* __restrict__ wout,
                                                const float* __restrict__ lpart,
                                                float* __restrict__ opart,
                                                float* __restrict__ l3) {
  int bh = blockIdx.x >> 2;
  int ks = blockIdx.x & 3;
  int b = bh >> 4, h = bh & 15;
  int t = threadIdx.x;
  int d = t & 63, ug = t >> 6;   // ug 0..15

  if (ks == 0 && t < UU) {
    float s = 0.f;
#pragma unroll
    for (int i = 0; i < 16; ++i) s += lpart[(bh * 16 + i) * UU + t];
    l3[bh * UU + t] = s;
  }

  __shared__ float ps[UU * 132];    // 20.1 KB
  __shared__ float vt[128 * 68];    // 34.8 KB
  float o0 = 0.f, o1 = 0.f, o2 = 0.f;
  bool has2 = (ug < 6);             // u = ug+32 < 38

  for (int chunk = 0; chunk < 4; ++chunk) {
    int c0 = ks * 512 + chunk * 128;
    __syncthreads();
    for (int i = t; i < UU * 32; i += 1024) {
      int u = i >> 5, d4 = i & 31;
      *(float4*)(ps + u * 132 + d4 * 4) =
          *(const float4*)(wout + ((size_t)(bh * UU + u)) * LQ + c0 + d4 * 4);
    }
    for (int i = t; i < 128 * 16; i += 1024) {
      int kk = i >> 4, d4 = i & 15;
      *(float4*)(vt + kk * 68 + d4 * 4) =
          *(const float4*)(V + ((size_t)(b * LQ + c0 + kk)) * DM + h * DH + d4 * 4);
    }
    __syncthreads();
#pragma unroll 4
    for (int j4 = 0; j4 < 128; j4 += 4) {
      float4 p0 = *(const float4*)(ps + ug * 132 + j4);
      float4 p1 = *(const float4*)(ps + (ug + 16) * 132 + j4);
      float4 p2 = has2 ? *(const float4*)(ps + (ug + 32) * 132 + j4)
                       : make_float4(0.f, 0.f, 0.f, 0.f);
      float v0 = vt[(j4 + 0) * 68 + d];
      float v1 = vt[(j4 + 1) * 68 + d];
      float v2 = vt[(j4 + 2) * 68 + d];
      float v3 = vt[(j4 + 3) * 68 + d];
      o0 = fmaf(p0.x, v0, o0); o0 = fmaf(p0.y, v1, o0);
      o0 = fmaf(p0.z, v2, o0); o0 = fmaf(p0.w, v3, o0);
      o1 = fmaf(p1.x, v0, o1); o1 = fmaf(p1.y, v1, o1);
      o1 = fmaf(p1.z, v2, o1); o1 = fmaf(p1.w, v3, o1);
      o2 = fmaf(p2.x, v0, o2); o2 = fmaf(p2.y, v1, o2);
      o2 = fmaf(p2.z, v2, o2); o2 = fmaf(p2.w, v3, o2);
    }
  }

  float* obase = opart + ((size_t)((bh * 4 + ks) * UU)) * DH;
  obase[(size_t)ug * DH + d] = o0;
  obase[(size_t)(ug + 16) * DH + d] = o1;
  if (has2) obase[(size_t)(ug + 32) * DH + d] = o2;
}

// ---------------------------------------------------------------------------
// Kernel 4: normalize weights; reduce opart (fixed order) + scatter into the
// (pre-zeroed) dense output. (unchanged, validated)
// ---------------------------------------------------------------------------
__global__ __launch_bounds__(256) void finalize_kernel(const int* __restrict__ sel,
                                                       const float* __restrict__ l3,
                                                       const float* __restrict__ opart,
                                                       float* __restrict__ out,
                                                       float* __restrict__ wout) {
  const int N1 = NBH * UU * LQ;
  const int N2 = NBH * UU * DH;
  int i = blockIdx.x * 256 + threadIdx.x;
  if (i < N1) {
    int bhu = i >> 11;
    wout[i] = wout[i] / l3[bhu];
  } else {
    int i2 = i - N1;
    if (i2 < N2) {
      int bhu = i2 >> 6, d = i2 & 63;
      int bh = bhu / UU;
      int u = bhu - bh * UU;
      int b = bh >> 4, h = bh & 15;
      float s = 0.f;
#pragma unroll
      for (int p = 0; p < 4; ++p)
        s += opart[((size_t)((bh * 4 + p) * UU + u)) * DH + d];
      out[((size_t)(b * LQ + sel[bhu])) * DM + h * DH + d] = s / l3[bhu];
    }
  }
}

extern "C" void kernel_launch(void* const* d_in, const int* in_sizes, int n_in,
                              void* d_out, int out_size, void* d_ws, size_t ws_size,
                              hipStream_t stream) {
  (void)in_sizes; (void)n_in; (void)ws_size;
  const float* Q = (const float*)d_in[0];
  const float* K = (const float*)d_in[1];
  const float* V = (const float*)d_in[2];
  float* out = (float*)d_out;
  float* wout = out + (size_t)4 * LQ * DM;
  double* vals = (double*)d_ws;
  int* sel = (int*)((char*)d_ws + OFF_SEL);
  float* l3 = (float*)((char*)d_ws + OFF_L3);
  float* lpart = (float*)((char*)d_ws + OFF_LPART);
  float* opart = (float*)((char*)d_ws + OFF_OPART);

  hipMemsetAsync(out, 0, (size_t)4 * LQ * DM * sizeof(float), stream);

  kl_mfma<<<1024, 256, 0, stream>>>(Q, K, vals);
  topk_kernel<<<NBH, 1024, 0, stream>>>(vals, sel);
  attn_w<<<NBH * 16, 256, 0, stream>>>(Q, K, sel, wout, lpart);
  attn_pv<<<NBH * 4, 1024, 0, stream>>>(V, wout, lpart, opart, l3);
  finalize_kernel<<<(NBH * UU * LQ + NBH * UU * DH + 255) / 256, 256, 0, stream>>>(
      sel, l3, opart, out, wout);
}

// Round 7
// 422.480 us; speedup vs baseline: 1.3467x; 1.0384x over previous
//
#include <hip/hip_runtime.h>
#include <math.h>

#define LQ 2048
#define DM 1024
#define NH 16
#define DH 64
#define UU 38
#define NBH 64            // B*NH = 4*16
#define SCALE 0.125f      // 1/sqrt(64)

typedef _Float16 f16x8 __attribute__((ext_vector_type(8)));
typedef float f32x4 __attribute__((ext_vector_type(4)));

// workspace layout (bytes):
//   [0, 1048576)           vals  : 131072 f64 (KL per query)
//   [1048576, +9728)       sel   : 64*38 int
//   [1058304, +9728)       l3    : 64*38 f32
//   [1068032, +311296)     lpart : [64][32][38] f32
//   [1379328, +2490368)    opart : [64][4][38][64] f32   (end 3869696)
#define OFF_SEL   1048576
#define OFF_L3    1058304
#define OFF_LPART 1068032
#define OFF_OPART 1379328

// ---------------------------------------------------------------------------
// Kernel 1: KL via fp16-split MFMA, round-7:
//  - Q A-frags loaded DIRECTLY from global (one-time, 8x16B per lane) -> the
//    34.8KB qs LDS stage is gone; LDS = khi/klo 16KB only -> LDS no longer
//    caps occupancy (was 4 blocks/CU, now 10 by LDS).
//  - Keep r6's conflict-free swizzled K layout (stride 64 halves, 16B-block
//    XOR swizzle blk^(key&7)) -- verified: conflicts 8.5M -> 131k.
//  - Keep r6's register prefetch pipeline + exp2 epilogue.
// ---------------------------------------------------------------------------
__global__ __launch_bounds__(256) void kl_mfma(const float* __restrict__ Q,
                                               const float* __restrict__ K,
                                               double* __restrict__ vals) {
  int bh = blockIdx.x & 63;
  int qc = blockIdx.x >> 6;
  int b = bh >> 4, h = bh & 15;
  int t = threadIdx.x;
  int lane = t & 63, w = t >> 6;
  int quad = lane >> 4, l15 = lane & 15;

  __shared__ __align__(16) _Float16 khi[64 * 64];   // 8 KB, swizzled 16B blocks
  __shared__ __align__(16) _Float16 klo[64 * 64];   // 8 KB

  const float* kbase = K + ((size_t)b * LQ) * DM + h * DH;

  // prefetch slots: thread t -> (key = s*32 + t/8, blk = t%8)
  int pkey0 = (t >> 3), pkey1 = 32 + (t >> 3);
  int pblk = t & 7;
  float4 pf00, pf01, pf10, pf11;
  {
    const float* s0 = kbase + (size_t)pkey0 * DM + pblk * 8;
    const float* s1 = kbase + (size_t)pkey1 * DM + pblk * 8;
    pf00 = *(const float4*)s0; pf01 = *(const float4*)(s0 + 4);
    pf10 = *(const float4*)s1; pf11 = *(const float4*)(s1 + 4);
  }

  // A-frags straight from global: lane reads Q[row = w*32+qt*16+l15],
  // dims c*32 + quad*8 .. +7 (two aligned float4s), split hi/lo once.
  f16x8 ahi[2][2], alo[2][2];
  {
    const float* qrow = Q + ((size_t)(b * LQ + qc * 128)) * DM + h * DH;
#pragma unroll
    for (int qt = 0; qt < 2; ++qt)
#pragma unroll
      for (int c = 0; c < 2; ++c) {
        const float* p = qrow + (size_t)(w * 32 + qt * 16 + l15) * DM + c * 32 + quad * 8;
        float4 x0 = *(const float4*)p;
        float4 x1 = *(const float4*)(p + 4);
        f16x8 hi, lo;
#define QCV(i, xx) { float x_ = (xx); _Float16 hh = (_Float16)x_; hi[i] = hh; lo[i] = (_Float16)(x_ - (float)hh); }
        QCV(0, x0.x) QCV(1, x0.y) QCV(2, x0.z) QCV(3, x0.w)
        QCV(4, x1.x) QCV(5, x1.y) QCV(6, x1.z) QCV(7, x1.w)
#undef QCV
        ahi[qt][c] = hi;
        alo[qt][c] = lo;
      }
  }

  int swb0 = pblk ^ (pkey0 & 7);
  int swb1 = pblk ^ (pkey1 & 7);
  int bsw0 = quad ^ (l15 & 7);            // B-frag swizzled blocks (c=0 / c=1)
  int bsw1 = (quad + 4) ^ (l15 & 7);

  const float C1 = 0.18033688011112042f;  // SCALE * log2(e)

  double l64[2][4], t64[2][4];
#pragma unroll
  for (int qt = 0; qt < 2; ++qt)
#pragma unroll
    for (int r = 0; r < 4; ++r) { l64[qt][r] = 0.0; t64[qt][r] = 0.0; }

  for (int kb = 0; kb < LQ; kb += 64) {
    // convert prefetched regs -> swizzled LDS
    {
      f16x8 hi, lo;
#define CV(i, xx) { float x_ = (xx); _Float16 hh = (_Float16)x_; hi[i] = hh; lo[i] = (_Float16)(x_ - (float)hh); }
      CV(0, pf00.x) CV(1, pf00.y) CV(2, pf00.z) CV(3, pf00.w)
      CV(4, pf01.x) CV(5, pf01.y) CV(6, pf01.z) CV(7, pf01.w)
      *(f16x8*)(khi + pkey0 * 64 + swb0 * 8) = hi;
      *(f16x8*)(klo + pkey0 * 64 + swb0 * 8) = lo;
      CV(0, pf10.x) CV(1, pf10.y) CV(2, pf10.z) CV(3, pf10.w)
      CV(4, pf11.x) CV(5, pf11.y) CV(6, pf11.z) CV(7, pf11.w)
      *(f16x8*)(khi + pkey1 * 64 + swb1 * 8) = hi;
      *(f16x8*)(klo + pkey1 * 64 + swb1 * 8) = lo;
#undef CV
    }
    __syncthreads();

    // prefetch next chunk (lands during compute below)
    if (kb + 64 < LQ) {
      const float* s0 = kbase + (size_t)(kb + 64 + pkey0) * DM + pblk * 8;
      const float* s1 = kbase + (size_t)(kb + 64 + pkey1) * DM + pblk * 8;
      pf00 = *(const float4*)s0; pf01 = *(const float4*)(s0 + 4);
      pf10 = *(const float4*)s1; pf11 = *(const float4*)(s1 + 4);
    }

    float l32[2][4], t32[2][4];
#pragma unroll
    for (int qt = 0; qt < 2; ++qt)
#pragma unroll
      for (int r = 0; r < 4; ++r) { l32[qt][r] = 0.f; t32[qt][r] = 0.f; }

#pragma unroll
    for (int kt = 0; kt < 4; ++kt) {
      int key = kt * 16 + l15;
      f16x8 bhi0 = *(const f16x8*)(khi + key * 64 + bsw0 * 8);
      f16x8 bhi1 = *(const f16x8*)(khi + key * 64 + bsw1 * 8);
      f16x8 blo0 = *(const f16x8*)(klo + key * 64 + bsw0 * 8);
      f16x8 blo1 = *(const f16x8*)(klo + key * 64 + bsw1 * 8);
#pragma unroll
      for (int qt = 0; qt < 2; ++qt) {
        f32x4 cacc = {0.f, 0.f, 0.f, 0.f};
        cacc = __builtin_amdgcn_mfma_f32_16x16x32_f16(alo[qt][0], bhi0, cacc, 0, 0, 0);
        cacc = __builtin_amdgcn_mfma_f32_16x16x32_f16(alo[qt][1], bhi1, cacc, 0, 0, 0);
        cacc = __builtin_amdgcn_mfma_f32_16x16x32_f16(ahi[qt][0], blo0, cacc, 0, 0, 0);
        cacc = __builtin_amdgcn_mfma_f32_16x16x32_f16(ahi[qt][1], blo1, cacc, 0, 0, 0);
        cacc = __builtin_amdgcn_mfma_f32_16x16x32_f16(ahi[qt][0], bhi0, cacc, 0, 0, 0);
        cacc = __builtin_amdgcn_mfma_f32_16x16x32_f16(ahi[qt][1], bhi1, cacc, 0, 0, 0);
#pragma unroll
        for (int r = 0; r < 4; ++r) {
          float rr = cacc[r];
          float e = exp2f(rr * C1);        // e^(rr*SCALE)
          l32[qt][r] += e;
          t32[qt][r] = fmaf(rr, e, t32[qt][r]);
        }
      }
    }
#pragma unroll
    for (int qt = 0; qt < 2; ++qt)
#pragma unroll
      for (int r = 0; r < 4; ++r) {
        l64[qt][r] += (double)l32[qt][r];
        t64[qt][r] += (double)t32[qt][r];
      }
    __syncthreads();   // compute reads done -> next convert may overwrite
  }

#pragma unroll
  for (int qt = 0; qt < 2; ++qt)
#pragma unroll
    for (int r = 0; r < 4; ++r) {
      double lv = l64[qt][r], tv = t64[qt][r];
#pragma unroll
      for (int m = 1; m < 16; m <<= 1) {
        lv += __shfl_xor(lv, m);
        tv += __shfl_xor(tv, m);
      }
      if (l15 == 0) {
        int qg = qc * 128 + w * 32 + qt * 16 + quad * 4 + r;
        vals[(size_t)bh * LQ + qg] = 0.125 * (tv / lv) - log(lv) + 7.624618986159398;
      }
    }
}

// ---------------------------------------------------------------------------
// Kernel 2: per-(b,h) top-38 by KL (fp64), descending, ties -> lower index.
// (unchanged, validated)
// ---------------------------------------------------------------------------
__global__ __launch_bounds__(1024) void topk_kernel(const double* __restrict__ vals_in,
                                                    int* __restrict__ idxout) {
  int bh = blockIdx.x;
  int t = threadIdx.x;
  int w = t >> 6;
  __shared__ double vals[LQ];
  __shared__ double bv[16];
  __shared__ int bi[16];
  vals[t] = vals_in[(size_t)bh * LQ + t];
  vals[t + 1024] = vals_in[(size_t)bh * LQ + t + 1024];
  __syncthreads();
  for (int u = 0; u < UU; ++u) {
    double v0 = vals[t], v1 = vals[t + 1024];
    double best = v0; int besti = t;
    if (v1 > best) { best = v1; besti = t + 1024; }
#pragma unroll
    for (int off = 32; off > 0; off >>= 1) {
      double ov = __shfl_down(best, off);
      int oi = __shfl_down(besti, off);
      if (ov > best || (ov == best && oi < besti)) { best = ov; besti = oi; }
    }
    if ((t & 63) == 0) { bv[w] = best; bi[w] = besti; }
    __syncthreads();
    if (t == 0) {
      double fb = bv[0]; int fi = bi[0];
      for (int w2 = 1; w2 < 16; ++w2) {
        if (bv[w2] > fb || (bv[w2] == fb && bi[w2] < fi)) { fb = bv[w2]; fi = bi[w2]; }
      }
      idxout[bh * UU + u] = fi;
      vals[fi] = -INFINITY;
    }
    __syncthreads();
  }
}

// ---------------------------------------------------------------------------
// Kernel 3a: weights, round-7: 64-key blocks (grid 64 bh x 32 splits = 2048)
// for 2x latency-hiding parallelism vs r6's 128-key blocks. Inner structure
// unchanged (validated). lpart widens to 32 splits.
// ---------------------------------------------------------------------------
__global__ __launch_bounds__(256) void attn_w(const float* __restrict__ Q,
                                              const float* __restrict__ K,
                                              const int* __restrict__ sel,
                                              float* __restrict__ wout,
                                              float* __restrict__ lpart) {
  int bh = blockIdx.x >> 5;
  int ks = blockIdx.x & 31;
  int b = bh >> 4, h = bh & 15;
  int t = threadIdx.x;
  int lane = t & 63, w = t >> 6;

  __shared__ float qs[UU * 68];
  __shared__ float4 kt[64 * 16];
  __shared__ float els[UU * 65];
  __shared__ float lw[4][UU];
  __shared__ int sidx[UU];

  if (t < UU) sidx[t] = sel[bh * UU + t];
  __syncthreads();
  for (int i = t; i < UU * 16; i += 256) {
    int u = i >> 4, d4 = i & 15;
    *(float4*)(qs + u * 68 + d4 * 4) =
        *(const float4*)(Q + ((size_t)(b * LQ + sidx[u])) * DM + h * DH + d4 * 4);
  }
  int k0 = ks * 64;
  for (int i = t; i < 64 * 16; i += 256) {
    int kk = i >> 4, d4 = i & 15;
    kt[i] = ((const float4*)(K + ((size_t)(b * LQ + k0 + kk)) * DM + h * DH))[d4];
  }
  __syncthreads();

  bool act = lane < UU;
  float4 qv[16];
  if (act) {
    const float4* qp = (const float4*)(qs + lane * 68);
#pragma unroll
    for (int i = 0; i < 16; ++i) qv[i] = qp[i];
  } else {
#pragma unroll
    for (int i = 0; i < 16; ++i) qv[i] = make_float4(0.f, 0.f, 0.f, 0.f);
  }

  float l_acc = 0.f;

#pragma unroll
  for (int jj = 0; jj < 16; ++jj) {
    int j = w * 16 + jj;
    const float4* krow = &kt[j * 16];
    float4 a = make_float4(0.f, 0.f, 0.f, 0.f);
    float4 c = make_float4(0.f, 0.f, 0.f, 0.f);
#pragma unroll
    for (int d4 = 0; d4 < 16; d4 += 2) {
      float4 k0v = krow[d4];
      float4 k1v = krow[d4 + 1];
      a.x = fmaf(qv[d4].x, k0v.x, a.x);
      a.y = fmaf(qv[d4].y, k0v.y, a.y);
      a.z = fmaf(qv[d4].z, k0v.z, a.z);
      a.w = fmaf(qv[d4].w, k0v.w, a.w);
      c.x = fmaf(qv[d4 + 1].x, k1v.x, c.x);
      c.y = fmaf(qv[d4 + 1].y, k1v.y, c.y);
      c.z = fmaf(qv[d4 + 1].z, k1v.z, c.z);
      c.w = fmaf(qv[d4 + 1].w, k1v.w, c.w);
    }
    float s = (((a.x + a.y) + (a.z + a.w)) + ((c.x + c.y) + (c.z + c.w))) * SCALE;
    float e = act ? __expf(s) : 0.f;
    if (act) els[lane * 65 + j] = e;
    l_acc += e;
  }
  __syncthreads();

  // coalesced dump: consecutive threads -> consecutive keys (256 B runs)
  for (int i = t; i < UU * 64; i += 256) {
    int u2 = i >> 6, j2 = i & 63;
    wout[((size_t)(bh * UU + u2)) * LQ + k0 + j2] = els[u2 * 65 + j2];
  }

  if (act) lw[w][lane] = l_acc;
  __syncthreads();
  if (t < UU)
    lpart[(bh * 32 + ks) * UU + t] = ((lw[0][t] + lw[1][t]) + (lw[2][t] + lw[3][t]));
}

// ---------------------------------------------------------------------------
// Kernel 3b: P*V partials (r6 structure, validated). lpart reduce now 32.
// ---------------------------------------------------------------------------
__global__ __launch_bounds__(1024) void attn_pv(const float* __restrict__ V,
                                                const float* __restrict__ wout,
                                                const float* __restrict__ lpart,
                                                float* __restrict__ opart,
                                                float* __restrict__ l3) {
  int bh = blockIdx.x >> 2;
  int ks = blockIdx.x & 3;
  int b = bh >> 4, h = bh & 15;
  int t = threadIdx.x;
  int d = t & 63, ug = t >> 6;   // ug 0..15

  if (ks == 0 && t < UU) {
    float s = 0.f;
#pragma unroll
    for (int i = 0; i < 32; ++i) s += lpart[(bh * 32 + i) * UU + t];
    l3[bh * UU + t] = s;
  }

  __shared__ float ps[UU * 132];    // 20.1 KB
  __shared__ float vt[128 * 68];    // 34.8 KB
  float o0 = 0.f, o1 = 0.f, o2 = 0.f;
  bool has2 = (ug < 6);             // u = ug+32 < 38

  for (int chunk = 0; chunk < 4; ++chunk) {
    int c0 = ks * 512 + chunk * 128;
    __syncthreads();
    for (int i = t; i < UU * 32; i += 1024) {
      int u = i >> 5, d4 = i & 31;
      *(float4*)(ps + u * 132 + d4 * 4) =
          *(const float4*)(wout + ((size_t)(bh * UU + u)) * LQ + c0 + d4 * 4);
    }
    for (int i = t; i < 128 * 16; i += 1024) {
      int kk = i >> 4, d4 = i & 15;
      *(float4*)(vt + kk * 68 + d4 * 4) =
          *(const float4*)(V + ((size_t)(b * LQ + c0 + kk)) * DM + h * DH + d4 * 4);
    }
    __syncthreads();
#pragma unroll 4
    for (int j4 = 0; j4 < 128; j4 += 4) {
      float4 p0 = *(const float4*)(ps + ug * 132 + j4);
      float4 p1 = *(const float4*)(ps + (ug + 16) * 132 + j4);
      float4 p2 = has2 ? *(const float4*)(ps + (ug + 32) * 132 + j4)
                       : make_float4(0.f, 0.f, 0.f, 0.f);
      float v0 = vt[(j4 + 0) * 68 + d];
      float v1 = vt[(j4 + 1) * 68 + d];
      float v2 = vt[(j4 + 2) * 68 + d];
      float v3 = vt[(j4 + 3) * 68 + d];
      o0 = fmaf(p0.x, v0, o0); o0 = fmaf(p0.y, v1, o0);
      o0 = fmaf(p0.z, v2, o0); o0 = fmaf(p0.w, v3, o0);
      o1 = fmaf(p1.x, v0, o1); o1 = fmaf(p1.y, v1, o1);
      o1 = fmaf(p1.z, v2, o1); o1 = fmaf(p1.w, v3, o1);
      o2 = fmaf(p2.x, v0, o2); o2 = fmaf(p2.y, v1, o2);
      o2 = fmaf(p2.z, v2, o2); o2 = fmaf(p2.w, v3, o2);
    }
  }

  float* obase = opart + ((size_t)((bh * 4 + ks) * UU)) * DH;
  obase[(size_t)ug * DH + d] = o0;
  obase[(size_t)(ug + 16) * DH + d] = o1;
  if (has2) obase[(size_t)(ug + 32) * DH + d] = o2;
}

// ---------------------------------------------------------------------------
// Kernel 4: normalize weights; reduce opart (fixed order) + scatter into the
// (pre-zeroed) dense output. (unchanged, validated)
// ---------------------------------------------------------------------------
__global__ __launch_bounds__(256) void finalize_kernel(const int* __restrict__ sel,
                                                       const float* __restrict__ l3,
                                                       const float* __restrict__ opart,
                                                       float* __restrict__ out,
                                                       float* __restrict__ wout) {
  const int N1 = NBH * UU * LQ;
  const int N2 = NBH * UU * DH;
  int i = blockIdx.x * 256 + threadIdx.x;
  if (i < N1) {
    int bhu = i >> 11;
    wout[i] = wout[i] / l3[bhu];
  } else {
    int i2 = i - N1;
    if (i2 < N2) {
      int bhu = i2 >> 6, d = i2 & 63;
      int bh = bhu / UU;
      int u = bhu - bh * UU;
      int b = bh >> 4, h = bh & 15;
      float s = 0.f;
#pragma unroll
      for (int p = 0; p < 4; ++p)
        s += opart[((size_t)((bh * 4 + p) * UU + u)) * DH + d];
      out[((size_t)(b * LQ + sel[bhu])) * DM + h * DH + d] = s / l3[bhu];
    }
  }
}

extern "C" void kernel_launch(void* const* d_in, const int* in_sizes, int n_in,
                              void* d_out, int out_size, void* d_ws, size_t ws_size,
                              hipStream_t stream) {
  (void)in_sizes; (void)n_in; (void)ws_size;
  const float* Q = (const float*)d_in[0];
  const float* K = (const float*)d_in[1];
  const float* V = (const float*)d_in[2];
  float* out = (float*)d_out;
  float* wout = out + (size_t)4 * LQ * DM;
  double* vals = (double*)d_ws;
  int* sel = (int*)((char*)d_ws + OFF_SEL);
  float* l3 = (float*)((char*)d_ws + OFF_L3);
  float* lpart = (float*)((char*)d_ws + OFF_LPART);
  float* opart = (float*)((char*)d_ws + OFF_OPART);

  hipMemsetAsync(out, 0, (size_t)4 * LQ * DM * sizeof(float), stream);

  kl_mfma<<<1024, 256, 0, stream>>>(Q, K, vals);
  topk_kernel<<<NBH, 1024, 0, stream>>>(vals, sel);
  attn_w<<<NBH * 32, 256, 0, stream>>>(Q, K, sel, wout, lpart);
  attn_pv<<<NBH * 4, 1024, 0, stream>>>(V, wout, lpart, opart, l3);
  finalize_kernel<<<(NBH * UU * LQ + NBH * UU * DH + 255) / 256, 256, 0, stream>>>(
      sel, l3, opart, out, wout);
}

// Round 8
// 418.086 us; speedup vs baseline: 1.3608x; 1.0105x over previous
//
#include <hip/hip_runtime.h>
#include <math.h>

#define LQ 2048
#define DM 1024
#define NH 16
#define DH 64
#define UU 38
#define NBH 64            // B*NH = 4*16
#define SCALE 0.125f      // 1/sqrt(64)

typedef _Float16 f16x8 __attribute__((ext_vector_type(8)));
typedef float f32x4 __attribute__((ext_vector_type(4)));

#if __has_builtin(__builtin_amdgcn_exp2f)
#define EXP2F(x) __builtin_amdgcn_exp2f(x)
#else
#define EXP2F(x) exp2f(x)
#endif

// ---- fast-path workspace layout (bytes) ----
//   lt    : [2][64][2048][2] f64          [0, 4194304)
//   sel   : 64*38 int                      +9728
//   l3    : 64*38 f32                      +9728
//   mask  : [64][2048] s8                  +131072
//   lpart : [64][32][38] f32               +311296
//   opart : [64][4][38][64] f32            +2490368   (end 7146496)
//   ksp   : [64][32][8192] f16 (hi|lo imgs) +33554432 (end 40700928)
#define F_OFF_SEL   4194304
#define F_OFF_L3    4204032
#define F_OFF_MASK  4213760
#define F_OFF_LPART 4344832
#define F_OFF_OPART 4656128
#define F_OFF_KSP   7146496
#define F_NEED      40700928ull
// ---- fallback layout (r7-compatible + mask) ----
#define S_OFF_SEL   1048576
#define S_OFF_L3    1058304
#define S_OFF_MASK  1068032
#define S_OFF_LPART 1199104
#define S_OFF_OPART 1510400

// ---------------------------------------------------------------------------
// ksplit: one-time K fp32 -> fp16 hi/lo split, stored in global with the
// conflict-free LDS image pre-baked: per (bh,kc) chunk, hi image [k*64+p*8+j]
// holds dims (p^(k&7))*8+j of key kc*64+k; lo image follows at +4096 halves.
// Removes ALL per-chunk conversion VALU from the kl hot loop (it was done
// redundantly 16x per bh).
// ---------------------------------------------------------------------------
__global__ __launch_bounds__(256) void ksplit_kernel(const float* __restrict__ K,
                                                     _Float16* __restrict__ ksp) {
  int idx = blockIdx.x * 256 + threadIdx.x;   // 1,048,576 total
  int p = idx & 7;
  int k = (idx >> 3) & 63;
  int kc = (idx >> 9) & 31;
  int bh = idx >> 14;
  int b = bh >> 4, h = bh & 15;
  const float* src = K + ((size_t)(b * LQ + kc * 64 + k)) * DM + h * DH + (p ^ (k & 7)) * 8;
  float4 x0 = *(const float4*)src;
  float4 x1 = *(const float4*)(src + 4);
  f16x8 hi, lo;
#define KCV(i, xx) { float x_ = (xx); _Float16 hh = (_Float16)x_; hi[i] = hh; lo[i] = (_Float16)(x_ - (float)hh); }
  KCV(0, x0.x) KCV(1, x0.y) KCV(2, x0.z) KCV(3, x0.w)
  KCV(4, x1.x) KCV(5, x1.y) KCV(6, x1.z) KCV(7, x1.w)
#undef KCV
  _Float16* base = ksp + ((size_t)(bh * 32 + kc)) * 8192;
  *(f16x8*)(base + k * 64 + p * 8) = hi;
  *(f16x8*)(base + 4096 + k * 64 + p * 8) = lo;
}

// ---------------------------------------------------------------------------
// kl_mfma2 (fast path): grid = 64 bh x 16 qc x 2 key-splits = 2048 blocks
// (8 blocks/CU). LDS = 16 KB (one chunk image). Staging = 4 uint4 copies per
// thread, no conversion. MFMA core + swizzled B-frag reads identical to the
// validated r7 kernel. Epilogue uses raw v_exp_f32. Writes (l, t') f64
// partials per query per split; KL assembled in topk2.
// ---------------------------------------------------------------------------
__global__ __launch_bounds__(256) void kl_mfma2(const float* __restrict__ Q,
                                                const _Float16* __restrict__ ksp,
                                                double* __restrict__ lt) {
  int bh = blockIdx.x & 63;
  int qc = (blockIdx.x >> 6) & 15;
  int sp = blockIdx.x >> 10;
  int b = bh >> 4, h = bh & 15;
  int t = threadIdx.x;
  int lane = t & 63, w = t >> 6;
  int quad = lane >> 4, l15 = lane & 15;

  __shared__ __align__(16) _Float16 kbuf[8192];   // hi [0,4096), lo [4096,8192)

  // A-frags straight from global (r7, validated)
  f16x8 ahi[2][2], alo[2][2];
  {
    const float* qrow = Q + ((size_t)(b * LQ + qc * 128)) * DM + h * DH;
#pragma unroll
    for (int qt = 0; qt < 2; ++qt)
#pragma unroll
      for (int c = 0; c < 2; ++c) {
        const float* p = qrow + (size_t)(w * 32 + qt * 16 + l15) * DM + c * 32 + quad * 8;
        float4 x0 = *(const float4*)p;
        float4 x1 = *(const float4*)(p + 4);
        f16x8 hi, lo;
#define QCV(i, xx) { float x_ = (xx); _Float16 hh = (_Float16)x_; hi[i] = hh; lo[i] = (_Float16)(x_ - (float)hh); }
        QCV(0, x0.x) QCV(1, x0.y) QCV(2, x0.z) QCV(3, x0.w)
        QCV(4, x1.x) QCV(5, x1.y) QCV(6, x1.z) QCV(7, x1.w)
#undef QCV
        ahi[qt][c] = hi;
        alo[qt][c] = lo;
      }
  }

  int bsw0 = quad ^ (l15 & 7);
  int bsw1 = (quad + 4) ^ (l15 & 7);
  _Float16* khi = kbuf;
  _Float16* klo = kbuf + 4096;
  const float C1 = 0.18033688011112042f;  // SCALE * log2(e)

  double l64[2][4], t64[2][4];
#pragma unroll
  for (int qt = 0; qt < 2; ++qt)
#pragma unroll
    for (int r = 0; r < 4; ++r) { l64[qt][r] = 0.0; t64[qt][r] = 0.0; }

  const uint4* gbase = (const uint4*)(ksp + ((size_t)(bh * 32 + sp * 16)) * 8192);
  uint4* lbuf = (uint4*)kbuf;

  for (int c = 0; c < 16; ++c) {
    const uint4* gsrc = gbase + (size_t)c * 1024;   // 16 KB per chunk
    __syncthreads();   // previous compute reads done
#pragma unroll
    for (int i = 0; i < 4; ++i) lbuf[i * 256 + t] = gsrc[i * 256 + t];
    __syncthreads();

    float l32[2][4], t32[2][4];
#pragma unroll
    for (int qt = 0; qt < 2; ++qt)
#pragma unroll
      for (int r = 0; r < 4; ++r) { l32[qt][r] = 0.f; t32[qt][r] = 0.f; }

#pragma unroll
    for (int kt = 0; kt < 4; ++kt) {
      int key = kt * 16 + l15;
      f16x8 bhi0 = *(const f16x8*)(khi + key * 64 + bsw0 * 8);
      f16x8 bhi1 = *(const f16x8*)(khi + key * 64 + bsw1 * 8);
      f16x8 blo0 = *(const f16x8*)(klo + key * 64 + bsw0 * 8);
      f16x8 blo1 = *(const f16x8*)(klo + key * 64 + bsw1 * 8);
#pragma unroll
      for (int qt = 0; qt < 2; ++qt) {
        f32x4 cacc = {0.f, 0.f, 0.f, 0.f};
        cacc = __builtin_amdgcn_mfma_f32_16x16x32_f16(alo[qt][0], bhi0, cacc, 0, 0, 0);
        cacc = __builtin_amdgcn_mfma_f32_16x16x32_f16(alo[qt][1], bhi1, cacc, 0, 0, 0);
        cacc = __builtin_amdgcn_mfma_f32_16x16x32_f16(ahi[qt][0], blo0, cacc, 0, 0, 0);
        cacc = __builtin_amdgcn_mfma_f32_16x16x32_f16(ahi[qt][1], blo1, cacc, 0, 0, 0);
        cacc = __builtin_amdgcn_mfma_f32_16x16x32_f16(ahi[qt][0], bhi0, cacc, 0, 0, 0);
        cacc = __builtin_amdgcn_mfma_f32_16x16x32_f16(ahi[qt][1], bhi1, cacc, 0, 0, 0);
#pragma unroll
        for (int r = 0; r < 4; ++r) {
          float rr = cacc[r];
          float e = EXP2F(rr * C1);          // e^(rr*SCALE), range-safe
          l32[qt][r] += e;
          t32[qt][r] = fmaf(rr, e, t32[qt][r]);
        }
      }
    }
#pragma unroll
    for (int qt = 0; qt < 2; ++qt)
#pragma unroll
      for (int r = 0; r < 4; ++r) {
        l64[qt][r] += (double)l32[qt][r];
        t64[qt][r] += (double)t32[qt][r];
      }
  }

#pragma unroll
  for (int qt = 0; qt < 2; ++qt)
#pragma unroll
    for (int r = 0; r < 4; ++r) {
      double lv = l64[qt][r], tv = t64[qt][r];
#pragma unroll
      for (int m = 1; m < 16; m <<= 1) {
        lv += __shfl_xor(lv, m);
        tv += __shfl_xor(tv, m);
      }
      if (l15 == 0) {
        int qg = qc * 128 + w * 32 + qt * 16 + quad * 4 + r;
        double* dst = lt + ((size_t)(sp * 64 + bh) * LQ + qg) * 2;
        dst[0] = lv;
        dst[1] = tv;
      }
    }
}

// ---------------------------------------------------------------------------
// kl_mfma_fb: fallback = exact r7 kernel (validated), writes KL directly.
// ---------------------------------------------------------------------------
__global__ __launch_bounds__(256) void kl_mfma_fb(const float* __restrict__ Q,
                                                  const float* __restrict__ K,
                                                  double* __restrict__ vals) {
  int bh = blockIdx.x & 63;
  int qc = blockIdx.x >> 6;
  int b = bh >> 4, h = bh & 15;
  int t = threadIdx.x;
  int lane = t & 63, w = t >> 6;
  int quad = lane >> 4, l15 = lane & 15;

  __shared__ __align__(16) _Float16 khi[64 * 64];
  __shared__ __align__(16) _Float16 klo[64 * 64];

  const float* kbase = K + ((size_t)b * LQ) * DM + h * DH;
  int pkey0 = (t >> 3), pkey1 = 32 + (t >> 3);
  int pblk = t & 7;
  float4 pf00, pf01, pf10, pf11;
  {
    const float* s0 = kbase + (size_t)pkey0 * DM + pblk * 8;
    const float* s1 = kbase + (size_t)pkey1 * DM + pblk * 8;
    pf00 = *(const float4*)s0; pf01 = *(const float4*)(s0 + 4);
    pf10 = *(const float4*)s1; pf11 = *(const float4*)(s1 + 4);
  }

  f16x8 ahi[2][2], alo[2][2];
  {
    const float* qrow = Q + ((size_t)(b * LQ + qc * 128)) * DM + h * DH;
#pragma unroll
    for (int qt = 0; qt < 2; ++qt)
#pragma unroll
      for (int c = 0; c < 2; ++c) {
        const float* p = qrow + (size_t)(w * 32 + qt * 16 + l15) * DM + c * 32 + quad * 8;
        float4 x0 = *(const float4*)p;
        float4 x1 = *(const float4*)(p + 4);
        f16x8 hi, lo;
#define QCV(i, xx) { float x_ = (xx); _Float16 hh = (_Float16)x_; hi[i] = hh; lo[i] = (_Float16)(x_ - (float)hh); }
        QCV(0, x0.x) QCV(1, x0.y) QCV(2, x0.z) QCV(3, x0.w)
        QCV(4, x1.x) QCV(5, x1.y) QCV(6, x1.z) QCV(7, x1.w)
#undef QCV
        ahi[qt][c] = hi;
        alo[qt][c] = lo;
      }
  }

  int swb0 = pblk ^ (pkey0 & 7);
  int swb1 = pblk ^ (pkey1 & 7);
  int bsw0 = quad ^ (l15 & 7);
  int bsw1 = (quad + 4) ^ (l15 & 7);
  const float C1 = 0.18033688011112042f;

  double l64[2][4], t64[2][4];
#pragma unroll
  for (int qt = 0; qt < 2; ++qt)
#pragma unroll
    for (int r = 0; r < 4; ++r) { l64[qt][r] = 0.0; t64[qt][r] = 0.0; }

  for (int kb = 0; kb < LQ; kb += 64) {
    {
      f16x8 hi, lo;
#define CV(i, xx) { float x_ = (xx); _Float16 hh = (_Float16)x_; hi[i] = hh; lo[i] = (_Float16)(x_ - (float)hh); }
      CV(0, pf00.x) CV(1, pf00.y) CV(2, pf00.z) CV(3, pf00.w)
      CV(4, pf01.x) CV(5, pf01.y) CV(6, pf01.z) CV(7, pf01.w)
      *(f16x8*)(khi + pkey0 * 64 + swb0 * 8) = hi;
      *(f16x8*)(klo + pkey0 * 64 + swb0 * 8) = lo;
      CV(0, pf10.x) CV(1, pf10.y) CV(2, pf10.z) CV(3, pf10.w)
      CV(4, pf11.x) CV(5, pf11.y) CV(6, pf11.z) CV(7, pf11.w)
      *(f16x8*)(khi + pkey1 * 64 + swb1 * 8) = hi;
      *(f16x8*)(klo + pkey1 * 64 + swb1 * 8) = lo;
#undef CV
    }
    __syncthreads();
    if (kb + 64 < LQ) {
      const float* s0 = kbase + (size_t)(kb + 64 + pkey0) * DM + pblk * 8;
      const float* s1 = kbase + (size_t)(kb + 64 + pkey1) * DM + pblk * 8;
      pf00 = *(const float4*)s0; pf01 = *(const float4*)(s0 + 4);
      pf10 = *(const float4*)s1; pf11 = *(const float4*)(s1 + 4);
    }
    float l32[2][4], t32[2][4];
#pragma unroll
    for (int qt = 0; qt < 2; ++qt)
#pragma unroll
      for (int r = 0; r < 4; ++r) { l32[qt][r] = 0.f; t32[qt][r] = 0.f; }
#pragma unroll
    for (int kt = 0; kt < 4; ++kt) {
      int key = kt * 16 + l15;
      f16x8 bhi0 = *(const f16x8*)(khi + key * 64 + bsw0 * 8);
      f16x8 bhi1 = *(const f16x8*)(khi + key * 64 + bsw1 * 8);
      f16x8 blo0 = *(const f16x8*)(klo + key * 64 + bsw0 * 8);
      f16x8 blo1 = *(const f16x8*)(klo + key * 64 + bsw1 * 8);
#pragma unroll
      for (int qt = 0; qt < 2; ++qt) {
        f32x4 cacc = {0.f, 0.f, 0.f, 0.f};
        cacc = __builtin_amdgcn_mfma_f32_16x16x32_f16(alo[qt][0], bhi0, cacc, 0, 0, 0);
        cacc = __builtin_amdgcn_mfma_f32_16x16x32_f16(alo[qt][1], bhi1, cacc, 0, 0, 0);
        cacc = __builtin_amdgcn_mfma_f32_16x16x32_f16(ahi[qt][0], blo0, cacc, 0, 0, 0);
        cacc = __builtin_amdgcn_mfma_f32_16x16x32_f16(ahi[qt][1], blo1, cacc, 0, 0, 0);
        cacc = __builtin_amdgcn_mfma_f32_16x16x32_f16(ahi[qt][0], bhi0, cacc, 0, 0, 0);
        cacc = __builtin_amdgcn_mfma_f32_16x16x32_f16(ahi[qt][1], bhi1, cacc, 0, 0, 0);
#pragma unroll
        for (int r = 0; r < 4; ++r) {
          float rr = cacc[r];
          float e = EXP2F(rr * C1);
          l32[qt][r] += e;
          t32[qt][r] = fmaf(rr, e, t32[qt][r]);
        }
      }
    }
#pragma unroll
    for (int qt = 0; qt < 2; ++qt)
#pragma unroll
      for (int r = 0; r < 4; ++r) {
        l64[qt][r] += (double)l32[qt][r];
        t64[qt][r] += (double)t32[qt][r];
      }
    __syncthreads();
  }

#pragma unroll
  for (int qt = 0; qt < 2; ++qt)
#pragma unroll
    for (int r = 0; r < 4; ++r) {
      double lv = l64[qt][r], tv = t64[qt][r];
#pragma unroll
      for (int m = 1; m < 16; m <<= 1) {
        lv += __shfl_xor(lv, m);
        tv += __shfl_xor(tv, m);
      }
      if (l15 == 0) {
        int qg = qc * 128 + w * 32 + qt * 16 + quad * 4 + r;
        vals[(size_t)bh * LQ + qg] = 0.125 * (tv / lv) - log(lv) + 7.624618986159398;
      }
    }
}

// ---------------------------------------------------------------------------
// topk2 (fast): combine 2 split partials -> KL (f64), then iterative top-38
// (ties -> lower index). Also emits selmask for writeout.
// ---------------------------------------------------------------------------
__global__ __launch_bounds__(1024) void topk2(const double* __restrict__ lt,
                                              int* __restrict__ idxout,
                                              signed char* __restrict__ selmask) {
  int bh = blockIdx.x;
  int t = threadIdx.x;
  int w = t >> 6;
  __shared__ double vals[LQ];
  __shared__ double bv[16];
  __shared__ int bi[16];
  const double logL = 7.624618986159398;
  for (int i = t; i < LQ; i += 1024) {
    const double* p0 = lt + ((size_t)bh * LQ + i) * 2;
    const double* p1 = lt + ((size_t)(64 + bh) * LQ + i) * 2;
    double l = p0[0] + p1[0];
    double tt = p0[1] + p1[1];
    vals[i] = 0.125 * (tt / l) - log(l) + logL;
    selmask[bh * LQ + i] = -1;
  }
  __syncthreads();
  for (int u = 0; u < UU; ++u) {
    double v0 = vals[t], v1 = vals[t + 1024];
    double best = v0; int besti = t;
    if (v1 > best) { best = v1; besti = t + 1024; }
#pragma unroll
    for (int off = 32; off > 0; off >>= 1) {
      double ov = __shfl_down(best, off);
      int oi = __shfl_down(besti, off);
      if (ov > best || (ov == best && oi < besti)) { best = ov; besti = oi; }
    }
    if ((t & 63) == 0) { bv[w] = best; bi[w] = besti; }
    __syncthreads();
    if (t == 0) {
      double fb = bv[0]; int fi = bi[0];
      for (int w2 = 1; w2 < 16; ++w2) {
        if (bv[w2] > fb || (bv[w2] == fb && bi[w2] < fi)) { fb = bv[w2]; fi = bi[w2]; }
      }
      idxout[bh * UU + u] = fi;
      selmask[bh * LQ + fi] = (signed char)u;
      vals[fi] = -INFINITY;
    }
    __syncthreads();
  }
}

// topk_fb (fallback): reads precomputed KL values.
__global__ __launch_bounds__(1024) void topk_fb(const double* __restrict__ vals_in,
                                                int* __restrict__ idxout,
                                                signed char* __restrict__ selmask) {
  int bh = blockIdx.x;
  int t = threadIdx.x;
  int w = t >> 6;
  __shared__ double vals[LQ];
  __shared__ double bv[16];
  __shared__ int bi[16];
  for (int i = t; i < LQ; i += 1024) {
    vals[i] = vals_in[(size_t)bh * LQ + i];
    selmask[bh * LQ + i] = -1;
  }
  __syncthreads();
  for (int u = 0; u < UU; ++u) {
    double v0 = vals[t], v1 = vals[t + 1024];
    double best = v0; int besti = t;
    if (v1 > best) { best = v1; besti = t + 1024; }
#pragma unroll
    for (int off = 32; off > 0; off >>= 1) {
      double ov = __shfl_down(best, off);
      int oi = __shfl_down(besti, off);
      if (ov > best || (ov == best && oi < besti)) { best = ov; besti = oi; }
    }
    if ((t & 63) == 0) { bv[w] = best; bi[w] = besti; }
    __syncthreads();
    if (t == 0) {
      double fb = bv[0]; int fi = bi[0];
      for (int w2 = 1; w2 < 16; ++w2) {
        if (bv[w2] > fb || (bv[w2] == fb && bi[w2] < fi)) { fb = bv[w2]; fi = bi[w2]; }
      }
      idxout[bh * UU + u] = fi;
      selmask[bh * LQ + fi] = (signed char)u;
      vals[fi] = -INFINITY;
    }
    __syncthreads();
  }
}

// ---------------------------------------------------------------------------
// attn_w (unchanged r7, validated): 64-key blocks, e^s -> wout + lpart.
// ---------------------------------------------------------------------------
__global__ __launch_bounds__(256) void attn_w(const float* __restrict__ Q,
                                              const float* __restrict__ K,
                                              const int* __restrict__ sel,
                                              float* __restrict__ wout,
                                              float* __restrict__ lpart) {
  int bh = blockIdx.x >> 5;
  int ks = blockIdx.x & 31;
  int b = bh >> 4, h = bh & 15;
  int t = threadIdx.x;
  int lane = t & 63, w = t >> 6;

  __shared__ float qs[UU * 68];
  __shared__ float4 kt[64 * 16];
  __shared__ float els[UU * 65];
  __shared__ float lw[4][UU];
  __shared__ int sidx[UU];

  if (t < UU) sidx[t] = sel[bh * UU + t];
  __syncthreads();
  for (int i = t; i < UU * 16; i += 256) {
    int u = i >> 4, d4 = i & 15;
    *(float4*)(qs + u * 68 + d4 * 4) =
        *(const float4*)(Q + ((size_t)(b * LQ + sidx[u])) * DM + h * DH + d4 * 4);
  }
  int k0 = ks * 64;
  for (int i = t; i < 64 * 16; i += 256) {
    int kk = i >> 4, d4 = i & 15;
    kt[i] = ((const float4*)(K + ((size_t)(b * LQ + k0 + kk)) * DM + h * DH))[d4];
  }
  __syncthreads();

  bool act = lane < UU;
  float4 qv[16];
  if (act) {
    const float4* qp = (const float4*)(qs + lane * 68);
#pragma unroll
    for (int i = 0; i < 16; ++i) qv[i] = qp[i];
  } else {
#pragma unroll
    for (int i = 0; i < 16; ++i) qv[i] = make_float4(0.f, 0.f, 0.f, 0.f);
  }

  float l_acc = 0.f;
#pragma unroll
  for (int jj = 0; jj < 16; ++jj) {
    int j = w * 16 + jj;
    const float4* krow = &kt[j * 16];
    float4 a = make_float4(0.f, 0.f, 0.f, 0.f);
    float4 c = make_float4(0.f, 0.f, 0.f, 0.f);
#pragma unroll
    for (int d4 = 0; d4 < 16; d4 += 2) {
      float4 k0v = krow[d4];
      float4 k1v = krow[d4 + 1];
      a.x = fmaf(qv[d4].x, k0v.x, a.x);
      a.y = fmaf(qv[d4].y, k0v.y, a.y);
      a.z = fmaf(qv[d4].z, k0v.z, a.z);
      a.w = fmaf(qv[d4].w, k0v.w, a.w);
      c.x = fmaf(qv[d4 + 1].x, k1v.x, c.x);
      c.y = fmaf(qv[d4 + 1].y, k1v.y, c.y);
      c.z = fmaf(qv[d4 + 1].z, k1v.z, c.z);
      c.w = fmaf(qv[d4 + 1].w, k1v.w, c.w);
    }
    float s = (((a.x + a.y) + (a.z + a.w)) + ((c.x + c.y) + (c.z + c.w))) * SCALE;
    float e = act ? __expf(s) : 0.f;
    if (act) els[lane * 65 + j] = e;
    l_acc += e;
  }
  __syncthreads();

  for (int i = t; i < UU * 64; i += 256) {
    int u2 = i >> 6, j2 = i & 63;
    wout[((size_t)(bh * UU + u2)) * LQ + k0 + j2] = els[u2 * 65 + j2];
  }

  if (act) lw[w][lane] = l_acc;
  __syncthreads();
  if (t < UU)
    lpart[(bh * 32 + ks) * UU + t] = ((lw[0][t] + lw[1][t]) + (lw[2][t] + lw[3][t]));
}

// ---------------------------------------------------------------------------
// attn_pv (unchanged r7, validated).
// ---------------------------------------------------------------------------
__global__ __launch_bounds__(1024) void attn_pv(const float* __restrict__ V,
                                                const float* __restrict__ wout,
                                                const float* __restrict__ lpart,
                                                float* __restrict__ opart,
                                                float* __restrict__ l3) {
  int bh = blockIdx.x >> 2;
  int ks = blockIdx.x & 3;
  int b = bh >> 4, h = bh & 15;
  int t = threadIdx.x;
  int d = t & 63, ug = t >> 6;

  if (ks == 0 && t < UU) {
    float s = 0.f;
#pragma unroll
    for (int i = 0; i < 32; ++i) s += lpart[(bh * 32 + i) * UU + t];
    l3[bh * UU + t] = s;
  }

  __shared__ float ps[UU * 132];
  __shared__ float vt[128 * 68];
  float o0 = 0.f, o1 = 0.f, o2 = 0.f;
  bool has2 = (ug < 6);

  for (int chunk = 0; chunk < 4; ++chunk) {
    int c0 = ks * 512 + chunk * 128;
    __syncthreads();
    for (int i = t; i < UU * 32; i += 1024) {
      int u = i >> 5, d4 = i & 31;
      *(float4*)(ps + u * 132 + d4 * 4) =
          *(const float4*)(wout + ((size_t)(bh * UU + u)) * LQ + c0 + d4 * 4);
    }
    for (int i = t; i < 128 * 16; i += 1024) {
      int kk = i >> 4, d4 = i & 15;
      *(float4*)(vt + kk * 68 + d4 * 4) =
          *(const float4*)(V + ((size_t)(b * LQ + c0 + kk)) * DM + h * DH + d4 * 4);
    }
    __syncthreads();
#pragma unroll 4
    for (int j4 = 0; j4 < 128; j4 += 4) {
      float4 p0 = *(const float4*)(ps + ug * 132 + j4);
      float4 p1 = *(const float4*)(ps + (ug + 16) * 132 + j4);
      float4 p2 = has2 ? *(const float4*)(ps + (ug + 32) * 132 + j4)
                       : make_float4(0.f, 0.f, 0.f, 0.f);
      float v0 = vt[(j4 + 0) * 68 + d];
      float v1 = vt[(j4 + 1) * 68 + d];
      float v2 = vt[(j4 + 2) * 68 + d];
      float v3 = vt[(j4 + 3) * 68 + d];
      o0 = fmaf(p0.x, v0, o0); o0 = fmaf(p0.y, v1, o0);
      o0 = fmaf(p0.z, v2, o0); o0 = fmaf(p0.w, v3, o0);
      o1 = fmaf(p1.x, v0, o1); o1 = fmaf(p1.y, v1, o1);
      o1 = fmaf(p1.z, v2, o1); o1 = fmaf(p1.w, v3, o1);
      o2 = fmaf(p2.x, v0, o2); o2 = fmaf(p2.y, v1, o2);
      o2 = fmaf(p2.z, v2, o2); o2 = fmaf(p2.w, v3, o2);
    }
  }

  float* obase = opart + ((size_t)((bh * 4 + ks) * UU)) * DH;
  obase[(size_t)ug * DH + d] = o0;
  obase[(size_t)(ug + 16) * DH + d] = o1;
  if (has2) obase[(size_t)(ug + 32) * DH + d] = o2;
}

// ---------------------------------------------------------------------------
// writeout: replaces memset(out) + finalize. Part 1 normalizes wout in place;
// part 2 writes the FULL dense output (zeros for non-selected rows, reduced
// opart/l3 for selected rows via selmask).
// ---------------------------------------------------------------------------
__global__ __launch_bounds__(256) void writeout_kernel(const signed char* __restrict__ selmask,
                                                       const float* __restrict__ l3,
                                                       const float* __restrict__ opart,
                                                       float* __restrict__ out,
                                                       float* __restrict__ wout) {
  const int N1 = NBH * UU * LQ;           // 4,980,736
  int i = blockIdx.x * 256 + threadIdx.x;
  if (i < N1) {
    wout[i] = wout[i] / l3[i >> 11];
  } else {
    int i2 = i - N1;                      // < 8,388,608 (exact grid)
    int d = i2 & 63;
    int h = (i2 >> 6) & 15;
    int q = (i2 >> 10) & 2047;
    int b = i2 >> 21;
    int bh = b * 16 + h;
    int u = selmask[bh * LQ + q];
    float val = 0.f;
    if (u >= 0) {
      float s = 0.f;
#pragma unroll
      for (int p = 0; p < 4; ++p)
        s += opart[((size_t)((bh * 4 + p) * UU + u)) * DH + d];
      val = s / l3[bh * UU + u];
    }
    out[i2] = val;
  }
}

extern "C" void kernel_launch(void* const* d_in, const int* in_sizes, int n_in,
                              void* d_out, int out_size, void* d_ws, size_t ws_size,
                              hipStream_t stream) {
  (void)in_sizes; (void)n_in;
  const float* Q = (const float*)d_in[0];
  const float* K = (const float*)d_in[1];
  const float* V = (const float*)d_in[2];
  float* out = (float*)d_out;
  float* wout = out + (size_t)4 * LQ * DM;
  char* ws = (char*)d_ws;

  int* sel;
  float* l3;
  signed char* mask;
  float* lpart;
  float* opart;

  if (ws_size >= F_NEED) {
    double* lt = (double*)ws;
    sel = (int*)(ws + F_OFF_SEL);
    l3 = (float*)(ws + F_OFF_L3);
    mask = (signed char*)(ws + F_OFF_MASK);
    lpart = (float*)(ws + F_OFF_LPART);
    opart = (float*)(ws + F_OFF_OPART);
    _Float16* ksp = (_Float16*)(ws + F_OFF_KSP);

    ksplit_kernel<<<4096, 256, 0, stream>>>(K, ksp);
    kl_mfma2<<<2048, 256, 0, stream>>>(Q, ksp, lt);
    topk2<<<NBH, 1024, 0, stream>>>(lt, sel, mask);
  } else {
    double* vals = (double*)ws;
    sel = (int*)(ws + S_OFF_SEL);
    l3 = (float*)(ws + S_OFF_L3);
    mask = (signed char*)(ws + S_OFF_MASK);
    lpart = (float*)(ws + S_OFF_LPART);
    opart = (float*)(ws + S_OFF_OPART);

    kl_mfma_fb<<<1024, 256, 0, stream>>>(Q, K, vals);
    topk_fb<<<NBH, 1024, 0, stream>>>(vals, sel, mask);
  }

  attn_w<<<NBH * 32, 256, 0, stream>>>(Q, K, sel, wout, lpart);
  attn_pv<<<NBH * 4, 1024, 0, stream>>>(V, wout, lpart, opart, l3);
  writeout_kernel<<<(NBH * UU * LQ + 4 * LQ * DM) / 256, 256, 0, stream>>>(
      mask, l3, opart, out, wout);
}

// Round 9
// 362.989 us; speedup vs baseline: 1.5674x; 1.1518x over previous
//
#include <hip/hip_runtime.h>
#include <math.h>

#define LQ 2048
#define DM 1024
#define NH 16
#define DH 64
#define UU 38
#define NBH 64            // B*NH = 4*16
#define SCALE 0.125f      // 1/sqrt(64)

typedef _Float16 f16x8 __attribute__((ext_vector_type(8)));
typedef float f32x4 __attribute__((ext_vector_type(4)));

#if __has_builtin(__builtin_amdgcn_exp2f)
#define EXP2F(x) __builtin_amdgcn_exp2f(x)
#else
#define EXP2F(x) exp2f(x)
#endif

// ---- workspace layout (bytes), total 40,700,928 (proven to fit in r8) ----
//   lt    : [2][64][2048][2] f64           [0, 4194304)
//   sel   : 64*38 int                       +9728
//   l3    : 64*38 f32                       +9728
//   mask  : [64][2048] s8                   +131072
//   lpart : [64][16][38] f32                +155648 (region 311296)
//   (gap to keep offsets stable)
//   ksp   : [64][32][8192] f16 @ 7146496    (33,554,432 B)
//   opart : [64][16][38][64] f32 ALIASES ksp (9.96 MB; written by attn_pv2
//           strictly after attn_w_mfma's last ksp read -- stream ordered)
#define F_OFF_SEL   4194304
#define F_OFF_L3    4204032
#define F_OFF_MASK  4213760
#define F_OFF_LPART 4344832
#define F_OFF_KSP   7146496
#define F_NEED      40700928ull

// ---------------------------------------------------------------------------
// ksplit: one-time K fp32 -> fp16 hi/lo split with the conflict-free LDS
// image pre-baked (dim-block p stored at p^(k&7)). Read by kl_mfma2 AND
// attn_w_mfma (second read is L2/L3-hot).
// ---------------------------------------------------------------------------
__global__ __launch_bounds__(256) void ksplit_kernel(const float* __restrict__ K,
                                                     _Float16* __restrict__ ksp) {
  int idx = blockIdx.x * 256 + threadIdx.x;   // 1,048,576 total
  int p = idx & 7;
  int k = (idx >> 3) & 63;
  int kc = (idx >> 9) & 31;
  int bh = idx >> 14;
  int b = bh >> 4, h = bh & 15;
  const float* src = K + ((size_t)(b * LQ + kc * 64 + k)) * DM + h * DH + (p ^ (k & 7)) * 8;
  float4 x0 = *(const float4*)src;
  float4 x1 = *(const float4*)(src + 4);
  f16x8 hi, lo;
#define KCV(i, xx) { float x_ = (xx); _Float16 hh = (_Float16)x_; hi[i] = hh; lo[i] = (_Float16)(x_ - (float)hh); }
  KCV(0, x0.x) KCV(1, x0.y) KCV(2, x0.z) KCV(3, x0.w)
  KCV(4, x1.x) KCV(5, x1.y) KCV(6, x1.z) KCV(7, x1.w)
#undef KCV
  _Float16* base = ksp + ((size_t)(bh * 32 + kc)) * 8192;
  *(f16x8*)(base + k * 64 + p * 8) = hi;
  *(f16x8*)(base + 4096 + k * 64 + p * 8) = lo;
}

// ---------------------------------------------------------------------------
// kl_mfma2: unchanged from r8 (validated, ~130 us; VALU 53 + MFMA 35 = 88%
// packed -- near this structure's floor).
// ---------------------------------------------------------------------------
__global__ __launch_bounds__(256) void kl_mfma2(const float* __restrict__ Q,
                                                const _Float16* __restrict__ ksp,
                                                double* __restrict__ lt) {
  int bh = blockIdx.x & 63;
  int qc = (blockIdx.x >> 6) & 15;
  int sp = blockIdx.x >> 10;
  int b = bh >> 4, h = bh & 15;
  int t = threadIdx.x;
  int lane = t & 63, w = t >> 6;
  int quad = lane >> 4, l15 = lane & 15;

  __shared__ __align__(16) _Float16 kbuf[8192];

  f16x8 ahi[2][2], alo[2][2];
  {
    const float* qrow = Q + ((size_t)(b * LQ + qc * 128)) * DM + h * DH;
#pragma unroll
    for (int qt = 0; qt < 2; ++qt)
#pragma unroll
      for (int c = 0; c < 2; ++c) {
        const float* p = qrow + (size_t)(w * 32 + qt * 16 + l15) * DM + c * 32 + quad * 8;
        float4 x0 = *(const float4*)p;
        float4 x1 = *(const float4*)(p + 4);
        f16x8 hi, lo;
#define QCV(i, xx) { float x_ = (xx); _Float16 hh = (_Float16)x_; hi[i] = hh; lo[i] = (_Float16)(x_ - (float)hh); }
        QCV(0, x0.x) QCV(1, x0.y) QCV(2, x0.z) QCV(3, x0.w)
        QCV(4, x1.x) QCV(5, x1.y) QCV(6, x1.z) QCV(7, x1.w)
#undef QCV
        ahi[qt][c] = hi;
        alo[qt][c] = lo;
      }
  }

  int bsw0 = quad ^ (l15 & 7);
  int bsw1 = (quad + 4) ^ (l15 & 7);
  _Float16* khi = kbuf;
  _Float16* klo = kbuf + 4096;
  const float C1 = 0.18033688011112042f;  // SCALE * log2(e)

  double l64[2][4], t64[2][4];
#pragma unroll
  for (int qt = 0; qt < 2; ++qt)
#pragma unroll
    for (int r = 0; r < 4; ++r) { l64[qt][r] = 0.0; t64[qt][r] = 0.0; }

  const uint4* gbase = (const uint4*)(ksp + ((size_t)(bh * 32 + sp * 16)) * 8192);
  uint4* lbuf = (uint4*)kbuf;

  for (int c = 0; c < 16; ++c) {
    const uint4* gsrc = gbase + (size_t)c * 1024;
    __syncthreads();
#pragma unroll
    for (int i = 0; i < 4; ++i) lbuf[i * 256 + t] = gsrc[i * 256 + t];
    __syncthreads();

    float l32[2][4], t32[2][4];
#pragma unroll
    for (int qt = 0; qt < 2; ++qt)
#pragma unroll
      for (int r = 0; r < 4; ++r) { l32[qt][r] = 0.f; t32[qt][r] = 0.f; }

#pragma unroll
    for (int kt = 0; kt < 4; ++kt) {
      int key = kt * 16 + l15;
      f16x8 bhi0 = *(const f16x8*)(khi + key * 64 + bsw0 * 8);
      f16x8 bhi1 = *(const f16x8*)(khi + key * 64 + bsw1 * 8);
      f16x8 blo0 = *(const f16x8*)(klo + key * 64 + bsw0 * 8);
      f16x8 blo1 = *(const f16x8*)(klo + key * 64 + bsw1 * 8);
#pragma unroll
      for (int qt = 0; qt < 2; ++qt) {
        f32x4 cacc = {0.f, 0.f, 0.f, 0.f};
        cacc = __builtin_amdgcn_mfma_f32_16x16x32_f16(alo[qt][0], bhi0, cacc, 0, 0, 0);
        cacc = __builtin_amdgcn_mfma_f32_16x16x32_f16(alo[qt][1], bhi1, cacc, 0, 0, 0);
        cacc = __builtin_amdgcn_mfma_f32_16x16x32_f16(ahi[qt][0], blo0, cacc, 0, 0, 0);
        cacc = __builtin_amdgcn_mfma_f32_16x16x32_f16(ahi[qt][1], blo1, cacc, 0, 0, 0);
        cacc = __builtin_amdgcn_mfma_f32_16x16x32_f16(ahi[qt][0], bhi0, cacc, 0, 0, 0);
        cacc = __builtin_amdgcn_mfma_f32_16x16x32_f16(ahi[qt][1], bhi1, cacc, 0, 0, 0);
#pragma unroll
        for (int r = 0; r < 4; ++r) {
          float rr = cacc[r];
          float e = EXP2F(rr * C1);
          l32[qt][r] += e;
          t32[qt][r] = fmaf(rr, e, t32[qt][r]);
        }
      }
    }
#pragma unroll
    for (int qt = 0; qt < 2; ++qt)
#pragma unroll
      for (int r = 0; r < 4; ++r) {
        l64[qt][r] += (double)l32[qt][r];
        t64[qt][r] += (double)t32[qt][r];
      }
  }

#pragma unroll
  for (int qt = 0; qt < 2; ++qt)
#pragma unroll
    for (int r = 0; r < 4; ++r) {
      double lv = l64[qt][r], tv = t64[qt][r];
#pragma unroll
      for (int m = 1; m < 16; m <<= 1) {
        lv += __shfl_xor(lv, m);
        tv += __shfl_xor(tv, m);
      }
      if (l15 == 0) {
        int qg = qc * 128 + w * 32 + qt * 16 + quad * 4 + r;
        double* dst = lt + ((size_t)(sp * 64 + bh) * LQ + qg) * 2;
        dst[0] = lv;
        dst[1] = tv;
      }
    }
}

// ---------------------------------------------------------------------------
// topk2: single wave per (b,h) -- ZERO barriers. Per-lane running max over 32
// LDS slots (lane owns elems i with i%64==lane); 6-step butterfly with
// tie->lowest-index (commutative/associative, all lanes converge); owner lane
// kills the winner and rescans its own slots only.
// ---------------------------------------------------------------------------
__global__ __launch_bounds__(64) void topk2(const double* __restrict__ lt,
                                            int* __restrict__ idxout,
                                            signed char* __restrict__ selmask) {
  int bh = blockIdx.x;
  int lane = threadIdx.x;
  __shared__ double vals[LQ];
  const double logL = 7.624618986159398;
  double bv = -INFINITY;
  int bi = LQ;
  for (int j = 0; j < 32; ++j) {
    int i = j * 64 + lane;
    const double* p0 = lt + ((size_t)bh * LQ + i) * 2;
    const double* p1 = lt + ((size_t)(64 + bh) * LQ + i) * 2;
    double l = p0[0] + p1[0];
    double tt = p0[1] + p1[1];
    double v = 0.125 * (tt / l) - log(l) + logL;
    vals[i] = v;
    selmask[bh * LQ + i] = -1;
    if (v > bv) { bv = v; bi = i; }   // ascending i -> strict > keeps lowest
  }
  for (int u = 0; u < UU; ++u) {
    double gv = bv;
    int gi = bi;
#pragma unroll
    for (int m = 1; m < 64; m <<= 1) {
      double ov = __shfl_xor(gv, m);
      int oi = __shfl_xor(gi, m);
      if (ov > gv || (ov == gv && oi < gi)) { gv = ov; gi = oi; }
    }
    if (lane == 0) {
      idxout[bh * UU + u] = gi;
      selmask[bh * LQ + gi] = (signed char)u;
    }
    if ((gi & 63) == lane) {     // only the owner's local state is stale
      vals[gi] = -INFINITY;
      bv = -INFINITY;
      bi = LQ;
      for (int j = 0; j < 32; ++j) {
        int i = j * 64 + lane;
        double v = vals[i];
        if (v > bv) { bv = v; bi = i; }
      }
    }
  }
}

// ---------------------------------------------------------------------------
// attn_w_mfma: weights via MFMA on the ksp K-cache. Grid = 64 bh x 16 ks
// (128 keys). 3 q-tiles (48 rows, clamped to u<=37), wave w owns k-tile w of
// each 64-key chunk. C layout: row=query-in-tile (quad*4+r), col=key (l15).
// e=exp2(raw*C1) -> els[48][132] -> coalesced wout dump + 64-lane shfl
// row-sums -> lpart (owner-written).
// ---------------------------------------------------------------------------
__global__ __launch_bounds__(256) void attn_w_mfma(const float* __restrict__ Q,
                                                   const _Float16* __restrict__ ksp,
                                                   const int* __restrict__ sel,
                                                   float* __restrict__ wout,
                                                   float* __restrict__ lpart) {
  int bh = blockIdx.x >> 4;
  int ks = blockIdx.x & 15;
  int b = bh >> 4, h = bh & 15;
  int t = threadIdx.x;
  int lane = t & 63, w = t >> 6;
  int quad = lane >> 4, l15 = lane & 15;

  __shared__ __align__(16) _Float16 kbuf[8192];   // 16 KB chunk image
  __shared__ float els[48 * 132];                 // 25.3 KB
  __shared__ int sidx[UU];

  if (t < UU) sidx[t] = sel[bh * UU + t];
  __syncthreads();

  f16x8 ahi[3][2], alo[3][2];
#pragma unroll
  for (int qt = 0; qt < 3; ++qt) {
    int u = qt * 16 + l15;
    if (u > 37) u = 37;                           // duplicate row 37 for pads
    const float* qrow = Q + ((size_t)(b * LQ + sidx[u])) * DM + h * DH;
#pragma unroll
    for (int c = 0; c < 2; ++c) {
      const float* p = qrow + c * 32 + quad * 8;
      float4 x0 = *(const float4*)p;
      float4 x1 = *(const float4*)(p + 4);
      f16x8 hi, lo;
#define QCV(i, xx) { float x_ = (xx); _Float16 hh = (_Float16)x_; hi[i] = hh; lo[i] = (_Float16)(x_ - (float)hh); }
      QCV(0, x0.x) QCV(1, x0.y) QCV(2, x0.z) QCV(3, x0.w)
      QCV(4, x1.x) QCV(5, x1.y) QCV(6, x1.z) QCV(7, x1.w)
#undef QCV
      ahi[qt][c] = hi;
      alo[qt][c] = lo;
    }
  }

  int bsw0 = quad ^ (l15 & 7);
  int bsw1 = (quad + 4) ^ (l15 & 7);
  const float C1 = 0.18033688011112042f;
  const uint4* gbase = (const uint4*)(ksp + ((size_t)(bh * 32 + ks * 2)) * 8192);
  uint4* lbuf = (uint4*)kbuf;
  _Float16* khi = kbuf;
  _Float16* klo = kbuf + 4096;

  for (int chunk = 0; chunk < 2; ++chunk) {
    __syncthreads();
#pragma unroll
    for (int i = 0; i < 4; ++i) lbuf[i * 256 + t] = gbase[chunk * 1024 + i * 256 + t];
    __syncthreads();
    int key = w * 16 + l15;
    f16x8 bhi0 = *(const f16x8*)(khi + key * 64 + bsw0 * 8);
    f16x8 bhi1 = *(const f16x8*)(khi + key * 64 + bsw1 * 8);
    f16x8 blo0 = *(const f16x8*)(klo + key * 64 + bsw0 * 8);
    f16x8 blo1 = *(const f16x8*)(klo + key * 64 + bsw1 * 8);
#pragma unroll
    for (int qt = 0; qt < 3; ++qt) {
      f32x4 cacc = {0.f, 0.f, 0.f, 0.f};
      cacc = __builtin_amdgcn_mfma_f32_16x16x32_f16(alo[qt][0], bhi0, cacc, 0, 0, 0);
      cacc = __builtin_amdgcn_mfma_f32_16x16x32_f16(alo[qt][1], bhi1, cacc, 0, 0, 0);
      cacc = __builtin_amdgcn_mfma_f32_16x16x32_f16(ahi[qt][0], blo0, cacc, 0, 0, 0);
      cacc = __builtin_amdgcn_mfma_f32_16x16x32_f16(ahi[qt][1], blo1, cacc, 0, 0, 0);
      cacc = __builtin_amdgcn_mfma_f32_16x16x32_f16(ahi[qt][0], bhi0, cacc, 0, 0, 0);
      cacc = __builtin_amdgcn_mfma_f32_16x16x32_f16(ahi[qt][1], bhi1, cacc, 0, 0, 0);
#pragma unroll
      for (int r = 0; r < 4; ++r) {
        float e = EXP2F(cacc[r] * C1);
        els[(qt * 16 + quad * 4 + r) * 132 + chunk * 64 + w * 16 + l15] = e;
      }
    }
  }
  __syncthreads();

  // coalesced dump (rows 38-47 never touched)
  for (int i = t; i < UU * 128; i += 256) {
    int u = i >> 7, k = i & 127;
    wout[((size_t)(bh * UU + u)) * LQ + ks * 128 + k] = els[u * 132 + k];
  }

  // row sums -> lpart: wave w reduces rows u = w + 4p
#pragma unroll
  for (int p = 0; p < 10; ++p) {
    int u = w + 4 * p;
    if (u < UU) {
      float s = els[u * 132 + lane] + els[u * 132 + 64 + lane];
#pragma unroll
      for (int m = 1; m < 64; m <<= 1) s += __shfl_xor(s, m);
      if (lane == 0) lpart[(bh * 16 + ks) * UU + u] = s;
    }
  }
}

// ---------------------------------------------------------------------------
// attn_pv2: grid = 64 bh x 16 ks (128 keys). P staged in LDS (broadcast
// reads); V read coalesced straight from global (each line read exactly once
// device-wide). Thread (ug=t>>6, d=t&63) accumulates u=ug+4p. opart (16
// partials) owner-written -- aliases ksp (safe: runs after attn_w_mfma).
// ks==0 also reduces lpart -> l3.
// ---------------------------------------------------------------------------
__global__ __launch_bounds__(256) void attn_pv2(const float* __restrict__ V,
                                                const float* __restrict__ wout,
                                                const float* __restrict__ lpart,
                                                float* __restrict__ opart,
                                                float* __restrict__ l3) {
  int bh = blockIdx.x >> 4;
  int ks = blockIdx.x & 15;
  int b = bh >> 4, h = bh & 15;
  int t = threadIdx.x;
  int d = t & 63, ug = t >> 6;

  if (ks == 0 && t < UU) {
    float s = 0.f;
#pragma unroll
    for (int i = 0; i < 16; ++i) s += lpart[(bh * 16 + i) * UU + t];
    l3[bh * UU + t] = s;
  }

  __shared__ float ps[40 * 132];   // rows 38,39 zeroed (pad accumulators)
  for (int i = t; i < UU * 32; i += 256) {
    int u = i >> 5, d4 = i & 31;
    *(float4*)(ps + u * 132 + d4 * 4) =
        *(const float4*)(wout + ((size_t)(bh * UU + u)) * LQ + ks * 128 + d4 * 4);
  }
  for (int i = t; i < 2 * 132; i += 256) ps[UU * 132 + i] = 0.f;
  __syncthreads();

  const float* vbase = V + ((size_t)(b * LQ + ks * 128)) * DM + h * DH + d;
  float o[10];
#pragma unroll
  for (int p = 0; p < 10; ++p) o[p] = 0.f;

  for (int j4 = 0; j4 < 128; j4 += 4) {
    float v0 = vbase[(size_t)(j4 + 0) * DM];
    float v1 = vbase[(size_t)(j4 + 1) * DM];
    float v2 = vbase[(size_t)(j4 + 2) * DM];
    float v3 = vbase[(size_t)(j4 + 3) * DM];
#pragma unroll
    for (int p = 0; p < 10; ++p) {
      float4 pw = *(const float4*)(ps + (ug + 4 * p) * 132 + j4);
      o[p] = fmaf(pw.x, v0, o[p]);
      o[p] = fmaf(pw.y, v1, o[p]);
      o[p] = fmaf(pw.z, v2, o[p]);
      o[p] = fmaf(pw.w, v3, o[p]);
    }
  }

#pragma unroll
  for (int p = 0; p < 10; ++p) {
    int u = ug + 4 * p;
    if (u < UU) opart[((size_t)((bh * 16 + ks) * UU + u)) * DH + d] = o[p];
  }
}

// ---------------------------------------------------------------------------
// writeout: part 1 normalizes wout in place; part 2 writes the full dense
// output (zeros for non-selected rows, 16-partial opart reduce for selected).
// ---------------------------------------------------------------------------
__global__ __launch_bounds__(256) void writeout_kernel(const signed char* __restrict__ selmask,
                                                       const float* __restrict__ l3,
                                                       const float* __restrict__ opart,
                                                       float* __restrict__ out,
                                                       float* __restrict__ wout) {
  const int N1 = NBH * UU * LQ;           // 4,980,736
  int i = blockIdx.x * 256 + threadIdx.x;
  if (i < N1) {
    wout[i] = wout[i] / l3[i >> 11];
  } else {
    int i2 = i - N1;                      // < 8,388,608 (exact grid)
    int d = i2 & 63;
    int h = (i2 >> 6) & 15;
    int q = (i2 >> 10) & 2047;
    int b = i2 >> 21;
    int bh = b * 16 + h;
    int u = selmask[bh * LQ + q];
    float val = 0.f;
    if (u >= 0) {
      float s = 0.f;
#pragma unroll
      for (int p = 0; p < 16; ++p)
        s += opart[((size_t)((bh * 16 + p) * UU + u)) * DH + d];
      val = s / l3[bh * UU + u];
    }
    out[i2] = val;
  }
}

extern "C" void kernel_launch(void* const* d_in, const int* in_sizes, int n_in,
                              void* d_out, int out_size, void* d_ws, size_t ws_size,
                              hipStream_t stream) {
  (void)in_sizes; (void)n_in;
  if (ws_size < F_NEED) return;   // fail visibly (poisoned out) over UB; r8 confirmed fit
  const float* Q = (const float*)d_in[0];
  const float* K = (const float*)d_in[1];
  const float* V = (const float*)d_in[2];
  float* out = (float*)d_out;
  float* wout = out + (size_t)4 * LQ * DM;
  char* ws = (char*)d_ws;

  double* lt = (double*)ws;
  int* sel = (int*)(ws + F_OFF_SEL);
  float* l3 = (float*)(ws + F_OFF_L3);
  signed char* mask = (signed char*)(ws + F_OFF_MASK);
  float* lpart = (float*)(ws + F_OFF_LPART);
  _Float16* ksp = (_Float16*)(ws + F_OFF_KSP);
  float* opart = (float*)(ws + F_OFF_KSP);   // aliases ksp, stream-ordered safe

  ksplit_kernel<<<4096, 256, 0, stream>>>(K, ksp);
  kl_mfma2<<<2048, 256, 0, stream>>>(Q, ksp, lt);
  topk2<<<NBH, 64, 0, stream>>>(lt, sel, mask);
  attn_w_mfma<<<NBH * 16, 256, 0, stream>>>(Q, ksp, sel, wout, lpart);
  attn_pv2<<<NBH * 16, 256, 0, stream>>>(V, wout, lpart, opart, l3);
  writeout_kernel<<<(NBH * UU * LQ + 4 * LQ * DM) / 256, 256, 0, stream>>>(
      mask, l3, opart, out, wout);
}